// Round 8
// baseline (2993.581 us; speedup 1.0000x reference)
//
#include <hip/hip_runtime.h>

#define B_ 8
#define R_ 128
#define T_ 64
#define FIN_ 32
#define L_ 64
#define D_ 64
#define H_ 128
#define OUT_ 32
#define ES_ 2048

typedef _Float16 f16;
typedef __attribute__((ext_vector_type(2))) _Float16 f16x2;
typedef __attribute__((ext_vector_type(8))) _Float16 f16x8;
typedef __attribute__((ext_vector_type(16))) float f32x16;
typedef __attribute__((ext_vector_type(2))) unsigned int u32x2;

__device__ __forceinline__ float silu_f(float x) { return x / (1.f + __expf(-x)); }
__device__ __forceinline__ float tanh_f(float x) {
    float e = __expf(2.f * x);
    return 1.f - 2.f / (e + 1.f);
}

// 256B-stride hi/lo-interleaved arrays: XOR row into 16B-granule bits.
__device__ __forceinline__ uint32_t swz256(uint32_t row, uint32_t s, uint32_t colByte) {
    uint32_t bo = row * 256u + s * 128u + colByte;
    return bo ^ ((row & 15u) << 4);
}

#define XA_OFF   0u       // 32 KB x buf0  [128 r][2 s][64 c] f16
#define XB_OFF   32768u   // 32 KB x buf1
#define WS_OFF   65536u   // 16 KB Wself^T [64 j][2 s][64 k] f16
#define WM_OFF   81920u   // 16 KB Wmsg^T
#define PRM_OFF  98304u   // CSR scratch: permS[2048], cnt[128], rs[129]
#define ODE_LDS  107584u  // A staging (64 KB fp32) aliases XA+XB pre-loop

__device__ __forceinline__ uint32_t pack2_f16(f16 a, f16 b) {
    union { f16x2 h; uint32_t u; } r;
    r.h[0] = a; r.h[1] = b;
    return r.u;
}

// ---------------------------------------------------------------------------
// encoder: one block per (b,r).
// ---------------------------------------------------------------------------
__global__ __launch_bounds__(256) void encoder_kernel(
    const float* __restrict__ node_feats, const float* __restrict__ eps,
    const float* __restrict__ W_e1, const float* __restrict__ b_e1,
    const float* __restrict__ W_e2, const float* __restrict__ b_e2,
    const float* __restrict__ W_mu, const float* __restrict__ W_sig,
    const float* __restrict__ W_dyn,
    float* __restrict__ Lz, float* __restrict__ Dz, float* __restrict__ dynb) {
    int br = blockIdx.x;
    int tid = threadIdx.x;
    __shared__ __align__(16) float xS[T_ * 36];
    __shared__ __align__(16) float h1[T_ * H_];
    __shared__ float hps[2 * H_];
    __shared__ float hp[H_];
    __shared__ float muS[H_], sgS[H_], vS[H_];

    const float* nf = node_feats + (size_t)br * (T_ * FIN_);
    for (int i = tid; i < T_ * FIN_; i += 256) {
        int t = i >> 5, f = i & 31;
        xS[t * 36 + f] = nf[i];
    }
    if (tid < T_) xS[tid * 36 + 32] = (float)tid * (1.f / 64.f);

    int j = tid & 127;
    int th = tid >> 7;
    float we1r[33];
    #pragma unroll
    for (int k = 0; k < 33; ++k) we1r[k] = W_e1[k * H_ + j];
    __syncthreads();

    float be1 = b_e1[j];
    for (int tt = 0; tt < 32; ++tt) {
        int t = th * 32 + tt;
        float a = be1;
        const float4* xr = (const float4*)(&xS[t * 36]);
        #pragma unroll
        for (int w4 = 0; w4 < 8; ++w4) {
            float4 xv = xr[w4];
            a += xv.x * we1r[w4 * 4 + 0] + xv.y * we1r[w4 * 4 + 1] +
                 xv.z * we1r[w4 * 4 + 2] + xv.w * we1r[w4 * 4 + 3];
        }
        a += xS[t * 36 + 32] * we1r[32];
        h1[t * H_ + j] = silu_f(a);
    }
    __syncthreads();

    float acc[32];
    float be2 = b_e2[j];
    #pragma unroll
    for (int tt = 0; tt < 32; ++tt) acc[tt] = be2;
    for (int kc = 0; kc < 4; ++kc) {
        float wreg[32];
        #pragma unroll
        for (int i2 = 0; i2 < 32; ++i2) wreg[i2] = W_e2[(kc * 32 + i2) * H_ + j];
        #pragma unroll
        for (int tt = 0; tt < 32; ++tt) {
            int t = th * 32 + tt;
            const float4* hrow = (const float4*)(&h1[t * H_ + kc * 32]);
            float s = 0.f;
            #pragma unroll
            for (int w4 = 0; w4 < 8; ++w4) {
                float4 hv = hrow[w4];
                s += hv.x * wreg[w4 * 4 + 0] + hv.y * wreg[w4 * 4 + 1] +
                     hv.z * wreg[w4 * 4 + 2] + hv.w * wreg[w4 * 4 + 3];
            }
            acc[tt] += s;
        }
    }
    float msum = 0.f;
    #pragma unroll
    for (int tt = 0; tt < 32; ++tt) msum += silu_f(acc[tt]);
    hps[th * H_ + j] = msum;
    __syncthreads();
    if (tid < H_) hp[tid] = (hps[tid] + hps[H_ + tid]) * (1.f / 64.f);
    __syncthreads();

    {
        const float* Wm = (th == 0) ? W_mu : W_sig;
        float a = 0.f;
        #pragma unroll 4
        for (int k = 0; k < H_; ++k) a += hp[k] * Wm[k * H_ + j];
        if (th == 0) muS[j] = a; else sgS[j] = a;
    }
    __syncthreads();
    if (tid < H_) {
        float sig = 0.1f + 0.9f / (1.f + __expf(-sgS[tid]));
        float v = muS[tid] + sig * eps[(size_t)br * H_ + tid];
        vS[tid] = v;
        if (tid < L_) Lz[(size_t)br * L_ + tid] = v;
        else          Dz[(size_t)br * D_ + (tid - L_)] = v;
    }
    __syncthreads();
    if (tid < L_) {
        float a = 0.f;
        #pragma unroll 4
        for (int k = 0; k < D_; ++k) a += vS[L_ + k] * W_dyn[k * L_ + tid];
        dynb[(size_t)br * L_ + tid] = a;
    }
}

// ---------------------------------------------------------------------------
// ode (MFMA, single-barrier): one block per batch, 8 waves. Per stage:
//   every wave computes the FULL M[:,cb] = x@Wmsg (4 row-tiles, redundant
//   across rb) + its own S tile; M never touches LDS: C-layout accumulators
//   are converted to A@M B-fragments in-register via pack + permlane32_swap.
//   Then accK = S + A@M, tanh, RK4, write x to the OTHER x buffer; 1 barrier.
// ---------------------------------------------------------------------------
__global__ __launch_bounds__(512, 2) void ode_kernel(
    const float* __restrict__ Lz, const float* __restrict__ dynb,
    const float* __restrict__ W_msg, const float* __restrict__ W_self,
    const float* __restrict__ b_ode,
    const int* __restrict__ src, const int* __restrict__ dst,
    const float* __restrict__ space_w,
    float* __restrict__ traj) {
    const int b = blockIdx.x;
    const int tid = threadIdx.x;
    const int lane = tid & 63;
    const int w = tid >> 6;          // 0..7
    const int rb = w & 3;            // output row block (32 rows)
    const int cb = w >> 2;           // output col block (32 cols)
    const int l31 = lane & 31;
    const int h = lane >> 5;
    const int cc = cb * 32 + l31;    // this thread's output column (0..63)

    extern __shared__ char sm[];
    float* Af = (float*)sm;                    // fp32 A staging [128][128]
    int* permS = (int*)(sm + PRM_OFF);         // 2048
    int* cntS  = permS + ES_;                  // 128
    int* rsS   = cntS + R_;                    // 129

    // ---- static weights -> LDS (hi/lo, transposed: WT[j][s][k] = W[k][j]) ----
    for (int idx = tid; idx < 4096; idx += 512) {
        int j = idx & 63, k = idx >> 6;
        float vs = W_self[k * 64 + j];
        f16 sh = (f16)vs;
        *(f16*)(sm + WS_OFF + swz256(j, 0, k * 2)) = sh;
        *(f16*)(sm + WS_OFF + swz256(j, 1, k * 2)) = (f16)(vs - (float)sh);
        float vm = W_msg[k * 64 + j];
        f16 mh = (f16)vm;
        *(f16*)(sm + WM_OFF + swz256(j, 0, k * 2)) = mh;
        *(f16*)(sm + WM_OFF + swz256(j, 1, k * 2)) = (f16)(vm - (float)mh);
    }
    // ---- CSR build (deterministic, per-block) ----
    if (tid < R_) {
        int c = 0;
        for (int e = 0; e < ES_; ++e) c += (dst[e] == tid) ? 1 : 0;
        cntS[tid] = c;
    }
    __syncthreads();
    if (tid == 0) {
        int a = 0;
        for (int i = 0; i < R_; ++i) { rsS[i] = a; a += cntS[i]; }
        rsS[R_] = a;
    }
    __syncthreads();
    if (tid < R_) {
        int k = rsS[tid];
        for (int e = 0; e < ES_; ++e)
            if (dst[e] == tid) permS[k++] = e;
    }
    for (int i = tid; i < 128 * 128; i += 512) Af[i] = 0.f;
    __syncthreads();
    if (tid < R_) {
        int e0_ = rsS[tid], e1_ = rsS[tid + 1];
        for (int e = e0_; e < e1_; ++e) {
            int pe = permS[e];
            Af[tid * 128 + src[pe]] += space_w[b * ES_ + pe];
        }
    }
    __syncthreads();

    // ---- A fragments -> VGPRs (hi/lo) ----
    f16x8 aH[8], aL[8];
    {
        int row = rb * 32 + l31;
        #pragma unroll
        for (int m = 0; m < 8; ++m) {
            const float* p = Af + row * 128 + m * 16 + h * 8;
            f16x8 vh, vl;
            #pragma unroll
            for (int i = 0; i < 8; ++i) {
                float v = p[i];
                f16 hi = (f16)v;
                vh[i] = hi;
                vl[i] = (f16)(v - (float)hi);
            }
            aH[m] = vh;
            aL[m] = vl;
        }
    }

    // ---- per-thread state in C-layout ----
    float xb[16], ks[16], dnb[16];
    {
        float bo = b_ode[cc];
        #pragma unroll
        for (int i = 0; i < 16; ++i) {
            int r = rb * 32 + (i & 3) + 8 * (i >> 2) + 4 * h;
            size_t o = ((size_t)(b * R_ + r)) * L_ + cc;
            xb[i] = Lz[o];
            dnb[i] = dynb[o] + bo;
        }
    }
    __syncthreads();  // Af dead; LDS 0..64KB becomes the x double-buffer

    // ---- write initial x into buf A ----
    #pragma unroll
    for (int i = 0; i < 16; ++i) {
        int r = rb * 32 + (i & 3) + 8 * (i >> 2) + 4 * h;
        f16 hi = (f16)xb[i];
        *(f16*)(sm + XA_OFF + swz256(r, 0, cc * 2)) = hi;
        *(f16*)(sm + XA_OFF + swz256(r, 1, cc * 2)) = (f16)(xb[i] - (float)hi);
    }
    __syncthreads();

    for (int n = 0; n < T_; ++n) {
        #pragma unroll
        for (int i = 0; i < 16; ++i) ks[i] = 0.f;
        #pragma unroll
        for (int s4 = 0; s4 < 4; ++s4) {
            const float wk = (s4 == 1 || s4 == 2) ? 2.f : 1.f;
            const float cn = (s4 < 2) ? 0.05f : 0.1f;
            const uint32_t bufC = (s4 & 1) ? XB_OFF : XA_OFF;
            const uint32_t bufN = bufC ^ 32768u;

            // ===== M = x@Wmsg (full 128 rows, 4 tiles) ; S = x[rb]@Wself =====
            f32x16 Mc0 = {}, Mc1 = {}, Mc2 = {}, Mc3 = {};
            f32x16 accS;
            #pragma unroll
            for (int i = 0; i < 16; ++i) accS[i] = dnb[i];
            #pragma unroll
            for (int ksq = 0; ksq < 4; ++ksq) {
                const uint32_t kB = (uint32_t)(ksq * 16 + 8 * h) * 2u;
                f16x8 wmH = *(const f16x8*)(sm + WM_OFF + swz256(cc, 0, kB));
                f16x8 wmL = *(const f16x8*)(sm + WM_OFF + swz256(cc, 1, kB));
                f16x8 wsH = *(const f16x8*)(sm + WS_OFF + swz256(cc, 0, kB));
                f16x8 wsL = *(const f16x8*)(sm + WS_OFF + swz256(cc, 1, kB));
                #define M_STEP(MC, MM)                                                     \
                do {                                                                       \
                    f16x8 xh = *(const f16x8*)(sm + bufC + swz256(32 * MM + l31, 0, kB));  \
                    f16x8 xl = *(const f16x8*)(sm + bufC + swz256(32 * MM + l31, 1, kB));  \
                    MC = __builtin_amdgcn_mfma_f32_32x32x16_f16(xh, wmH, MC, 0, 0, 0);     \
                    MC = __builtin_amdgcn_mfma_f32_32x32x16_f16(xl, wmH, MC, 0, 0, 0);     \
                    MC = __builtin_amdgcn_mfma_f32_32x32x16_f16(xh, wmL, MC, 0, 0, 0);     \
                    if (MM == rb) {                                                        \
                        accS = __builtin_amdgcn_mfma_f32_32x32x16_f16(xh, wsH, accS, 0, 0, 0); \
                        accS = __builtin_amdgcn_mfma_f32_32x32x16_f16(xl, wsH, accS, 0, 0, 0); \
                        accS = __builtin_amdgcn_mfma_f32_32x32x16_f16(xh, wsL, accS, 0, 0, 0); \
                    }                                                                      \
                } while (0)
                M_STEP(Mc0, 0);
                M_STEP(Mc1, 1);
                M_STEP(Mc2, 2);
                M_STEP(Mc3, 3);
                #undef M_STEP
            }

            // ===== convert Mc tiles -> A@M B-fragments (in-register) =====
            // C-layout reg j of tile m = M[32m + (j&3)+8(j>>2)+4h''][cc].
            // Pack pairs into dwords, permlane32_swap (d0,d2),(d1,d3) ->
            // k-ordered frag dwords for both lane halves (rows 16t+8h+i).
            f16x8 fH[8], fL[8];
            #define CONV(MC, MM)                                                           \
            do {                                                                           \
                uint32_t dh[8], dl[8];                                                     \
                _Pragma("unroll")                                                          \
                for (int jj = 0; jj < 8; ++jj) {                                           \
                    float v0 = MC[2 * jj], v1 = MC[2 * jj + 1];                            \
                    f16 h0 = (f16)v0, h1 = (f16)v1;                                        \
                    dh[jj] = pack2_f16(h0, h1);                                            \
                    dl[jj] = pack2_f16((f16)(v0 - (float)h0), (f16)(v1 - (float)h1));      \
                }                                                                          \
                u32x2 sA = __builtin_amdgcn_permlane32_swap(dh[0], dh[2], false, false);   \
                u32x2 sB = __builtin_amdgcn_permlane32_swap(dh[1], dh[3], false, false);   \
                u32x2 sC = __builtin_amdgcn_permlane32_swap(dh[4], dh[6], false, false);   \
                u32x2 sD = __builtin_amdgcn_permlane32_swap(dh[5], dh[7], false, false);   \
                union { uint32_t u[4]; f16x8 v; } t0, t1;                                  \
                t0.u[0] = sA[0]; t0.u[1] = sB[0]; t0.u[2] = sA[1]; t0.u[3] = sB[1];        \
                t1.u[0] = sC[0]; t1.u[1] = sD[0]; t1.u[2] = sC[1]; t1.u[3] = sD[1];        \
                fH[2 * MM] = t0.v; fH[2 * MM + 1] = t1.v;                                  \
                sA = __builtin_amdgcn_permlane32_swap(dl[0], dl[2], false, false);         \
                sB = __builtin_amdgcn_permlane32_swap(dl[1], dl[3], false, false);         \
                sC = __builtin_amdgcn_permlane32_swap(dl[4], dl[6], false, false);         \
                sD = __builtin_amdgcn_permlane32_swap(dl[5], dl[7], false, false);         \
                t0.u[0] = sA[0]; t0.u[1] = sB[0]; t0.u[2] = sA[1]; t0.u[3] = sB[1];        \
                t1.u[0] = sC[0]; t1.u[1] = sD[0]; t1.u[2] = sC[1]; t1.u[3] = sD[1];        \
                fL[2 * MM] = t0.v; fL[2 * MM + 1] = t1.v;                                  \
            } while (0)
            CONV(Mc0, 0);
            CONV(Mc1, 1);
            CONV(Mc2, 2);
            CONV(Mc3, 3);
            #undef CONV

            // ===== accK = S + A@M (chains: e0 kk0-2, e1 kk3-5, accS kk6-7) =====
            f32x16 e0 = {}, e1 = {};
            #define AM_STEP(KK, ACC)                                                       \
                ACC = __builtin_amdgcn_mfma_f32_32x32x16_f16(aH[KK], fH[KK], ACC, 0, 0, 0);\
                ACC = __builtin_amdgcn_mfma_f32_32x32x16_f16(aL[KK], fH[KK], ACC, 0, 0, 0);\
                ACC = __builtin_amdgcn_mfma_f32_32x32x16_f16(aH[KK], fL[KK], ACC, 0, 0, 0);
            AM_STEP(0, e0)
            AM_STEP(1, e0)
            AM_STEP(2, e0)
            AM_STEP(3, e1)
            AM_STEP(4, e1)
            AM_STEP(5, e1)
            AM_STEP(6, accS)
            AM_STEP(7, accS)
            #undef AM_STEP

            // ===== epilogue: tanh, RK4, write x to the other buffer =====
            float xn_[16];
            #pragma unroll
            for (int i = 0; i < 16; ++i) {
                float kv = tanh_f(accS[i] + e0[i] + e1[i]);
                ks[i] += wk * kv;
                xn_[i] = (s4 < 3) ? (xb[i] + cn * kv) : (xb[i] + (0.1f / 6.f) * ks[i]);
            }
            if (s4 == 3) {
                #pragma unroll
                for (int i = 0; i < 16; ++i) xb[i] = xn_[i];
            }
            #pragma unroll
            for (int i = 0; i < 16; ++i) {
                int r = rb * 32 + (i & 3) + 8 * (i >> 2) + 4 * h;
                f16 hi = (f16)xn_[i];
                *(f16*)(sm + bufN + swz256(r, 0, cc * 2)) = hi;
                *(f16*)(sm + bufN + swz256(r, 1, cc * 2)) = (f16)(xn_[i] - (float)hi);
            }
            if (s4 == 3) {
                #pragma unroll
                for (int i = 0; i < 16; ++i) {
                    int r = rb * 32 + (i & 3) + 8 * (i >> 2) + 4 * h;
                    traj[(((size_t)b * T_ + n) * R_ + r) * L_ + cc] = xb[i];
                }
            }
            __syncthreads();  // single barrier per stage
        }
    }
}

// ---------------------------------------------------------------------------
// decoder: one block per (b,r), one-hot rid exploited as row lookup.
// ---------------------------------------------------------------------------
__global__ __launch_bounds__(256) void decoder_kernel(
    const float* __restrict__ traj, const float* __restrict__ Dz,
    const float* __restrict__ W_d1, const float* __restrict__ b_d1,
    const float* __restrict__ W_d2, const float* __restrict__ b_d2,
    float* __restrict__ y) {
    int br = blockIdx.x;
    int b = br >> 7;
    int r = br & 127;
    int tid = threadIdx.x;
    __shared__ __align__(16) float trajS[32 * L_];
    __shared__ __align__(16) float hS[32 * H_];
    __shared__ float dzS[D_];
    __shared__ float baseS[H_];

    int j = tid & 127;
    int th = tid >> 7;
    if (tid < D_) dzS[tid] = Dz[(size_t)br * D_ + tid];
    __syncthreads();

    float wcol[64];
    #pragma unroll
    for (int k = 0; k < 64; ++k) wcol[k] = W_d1[k * H_ + j];
    float wt = W_d1[128 * H_ + j];
    if (th == 0) {
        float a = b_d1[j] + W_d1[(129 + r) * H_ + j];
        #pragma unroll 4
        for (int k = 0; k < D_; ++k) a += dzS[k] * W_d1[(64 + k) * H_ + j];
        baseS[j] = a;
    }
    __syncthreads();
    float bb = baseS[j];

    for (int half = 0; half < 2; ++half) {
        for (int i = tid; i < 32 * L_; i += 256) {
            int tt = i >> 6, l = i & 63;
            trajS[i] = traj[(((size_t)b * T_ + half * 32 + tt) * R_ + r) * L_ + l];
        }
        __syncthreads();
        #pragma unroll
        for (int tt = 0; tt < 16; ++tt) {
            int tl = th * 16 + tt;
            int t = half * 32 + tl;
            float a = bb + (float)t * (1.f / 64.f) * wt;
            const float4* tr4 = (const float4*)(&trajS[tl * L_]);
            #pragma unroll
            for (int kb = 0; kb < 16; ++kb) {
                float4 tv = tr4[kb];
                a += tv.x * wcol[kb * 4 + 0] + tv.y * wcol[kb * 4 + 1] +
                     tv.z * wcol[kb * 4 + 2] + tv.w * wcol[kb * 4 + 3];
            }
            hS[tl * H_ + j] = silu_f(a);
        }
        __syncthreads();
        {
            int o = tid & 31, q = tid >> 5;
            float acc2[4];
            float bd2 = b_d2[o];
            #pragma unroll
            for (int u = 0; u < 4; ++u) acc2[u] = bd2;
            for (int jc = 0; jc < 4; ++jc) {
                float wreg[32];
                #pragma unroll
                for (int i2 = 0; i2 < 32; ++i2) wreg[i2] = W_d2[(jc * 32 + i2) * OUT_ + o];
                #pragma unroll
                for (int u = 0; u < 4; ++u) {
                    int tl = q * 4 + u;
                    const float4* h4 = (const float4*)(&hS[tl * H_ + jc * 32]);
                    float s2 = 0.f;
                    #pragma unroll
                    for (int w4 = 0; w4 < 8; ++w4) {
                        float4 hv = h4[w4];
                        s2 += hv.x * wreg[w4 * 4 + 0] + hv.y * wreg[w4 * 4 + 1] +
                              hv.z * wreg[w4 * 4 + 2] + hv.w * wreg[w4 * 4 + 3];
                    }
                    acc2[u] += s2;
                }
            }
            #pragma unroll
            for (int u = 0; u < 4; ++u) {
                int t = half * 32 + q * 4 + u;
                y[((size_t)br * T_ + t) * OUT_ + o] = acc2[u];
            }
        }
        __syncthreads();
    }
}

extern "C" void kernel_launch(void* const* d_in, const int* in_sizes, int n_in,
                              void* d_out, int out_size, void* d_ws, size_t ws_size,
                              hipStream_t stream) {
    const float* node_feats = (const float*)d_in[0];
    const float* eps_       = (const float*)d_in[1];
    const float* space_w    = (const float*)d_in[2];
    const int*   src        = (const int*)d_in[3];
    const int*   dst        = (const int*)d_in[4];
    const float* W_e1 = (const float*)d_in[5];
    const float* b_e1 = (const float*)d_in[6];
    const float* W_e2 = (const float*)d_in[7];
    const float* b_e2 = (const float*)d_in[8];
    const float* W_mu = (const float*)d_in[9];
    const float* W_sig = (const float*)d_in[10];
    const float* W_msg = (const float*)d_in[11];
    const float* W_self = (const float*)d_in[12];
    const float* W_dyn = (const float*)d_in[13];
    const float* b_ode = (const float*)d_in[14];
    const float* W_d1 = (const float*)d_in[15];
    const float* b_d1 = (const float*)d_in[16];
    const float* W_d2 = (const float*)d_in[17];
    const float* b_d2 = (const float*)d_in[18];
    float* out = (float*)d_out;

    float* f_ws = (float*)d_ws;
    float* Lz    = f_ws;                              // 65536
    float* Dz    = Lz + B_ * R_ * L_;                 // 65536
    float* dynb  = Dz + B_ * R_ * D_;                 // 65536
    float* traj  = dynb + B_ * R_ * L_;               // 4194304

    encoder_kernel<<<B_ * R_, 256, 0, stream>>>(node_feats, eps_, W_e1, b_e1, W_e2, b_e2,
                                                W_mu, W_sig, W_dyn, Lz, Dz, dynb);
    ode_kernel<<<B_, 512, ODE_LDS, stream>>>(Lz, dynb, W_msg, W_self, b_ode,
                                             src, dst, space_w, traj);
    decoder_kernel<<<B_ * R_, 256, 0, stream>>>(traj, Dz, W_d1, b_d1, W_d2, b_d2, out);
}

// Round 9
// 1635.558 us; speedup vs baseline: 1.8303x; 1.8303x over previous
//
#include <hip/hip_runtime.h>

#define B_ 8
#define R_ 128
#define T_ 64
#define FIN_ 32
#define L_ 64
#define D_ 64
#define H_ 128
#define OUT_ 32
#define ES_ 2048

typedef _Float16 f16;
typedef __attribute__((ext_vector_type(2))) _Float16 f16x2;
typedef __attribute__((ext_vector_type(4))) _Float16 f16x4;
typedef __attribute__((ext_vector_type(8))) _Float16 f16x8;
typedef __attribute__((ext_vector_type(16))) float f32x16;

__device__ __forceinline__ float silu_f(float x) { return x / (1.f + __expf(-x)); }
__device__ __forceinline__ float tanh_f(float x) {
    float e = __expf(2.f * x);
    return 1.f - 2.f / (e + 1.f);
}

// 256B-stride hi/lo-interleaved arrays: XOR row into 16B-granule bits.
__device__ __forceinline__ uint32_t swz256(uint32_t row, uint32_t s, uint32_t colByte) {
    uint32_t bo = row * 256u + s * 128u + colByte;
    return bo ^ ((row & 15u) << 4);
}
// M^T: [64 c][2 s][128 r] f16, 512B rows.
__device__ __forceinline__ uint32_t swzT(uint32_t c, uint32_t s, uint32_t rByte) {
    uint32_t bo = c * 512u + s * 256u + rByte;
    return bo ^ ((c & 31u) << 4);
}

#define XROW_OFF 0u       // 32 KB x hi/lo   [128 r][2 s][64 c] f16
#define MT_OFF   32768u   // 32 KB M^T       [64 c][2 s][128 r] f16
#define WS_OFF   65536u   // 16 KB Wself^T   [64 j][2 s][64 k] f16
#define WM_OFF   81920u   // 16 KB Wmsg^T
#define PRM_OFF  98304u   // CSR scratch: permS[2048], cnt[128], rs[129]
#define ODE_LDS  107584u  // A staging (64 KB fp32) aliases XROW+MT pre-loop

// ---------------------------------------------------------------------------
// encoder: one block per (b,r).  (R6 version, unchanged)
// ---------------------------------------------------------------------------
__global__ __launch_bounds__(256) void encoder_kernel(
    const float* __restrict__ node_feats, const float* __restrict__ eps,
    const float* __restrict__ W_e1, const float* __restrict__ b_e1,
    const float* __restrict__ W_e2, const float* __restrict__ b_e2,
    const float* __restrict__ W_mu, const float* __restrict__ W_sig,
    const float* __restrict__ W_dyn,
    float* __restrict__ Lz, float* __restrict__ Dz, float* __restrict__ dynb) {
    int br = blockIdx.x;
    int tid = threadIdx.x;
    __shared__ __align__(16) float xS[T_ * 36];
    __shared__ __align__(16) float h1[T_ * H_];
    __shared__ float hps[2 * H_];
    __shared__ float hp[H_];
    __shared__ float muS[H_], sgS[H_], vS[H_];

    const float* nf = node_feats + (size_t)br * (T_ * FIN_);
    for (int i = tid; i < T_ * FIN_; i += 256) {
        int t = i >> 5, f = i & 31;
        xS[t * 36 + f] = nf[i];
    }
    if (tid < T_) xS[tid * 36 + 32] = (float)tid * (1.f / 64.f);

    int j = tid & 127;
    int th = tid >> 7;
    float we1r[33];
    #pragma unroll
    for (int k = 0; k < 33; ++k) we1r[k] = W_e1[k * H_ + j];
    __syncthreads();

    float be1 = b_e1[j];
    for (int tt = 0; tt < 32; ++tt) {
        int t = th * 32 + tt;
        float a = be1;
        const float4* xr = (const float4*)(&xS[t * 36]);
        #pragma unroll
        for (int w4 = 0; w4 < 8; ++w4) {
            float4 xv = xr[w4];
            a += xv.x * we1r[w4 * 4 + 0] + xv.y * we1r[w4 * 4 + 1] +
                 xv.z * we1r[w4 * 4 + 2] + xv.w * we1r[w4 * 4 + 3];
        }
        a += xS[t * 36 + 32] * we1r[32];
        h1[t * H_ + j] = silu_f(a);
    }
    __syncthreads();

    float acc[32];
    float be2 = b_e2[j];
    #pragma unroll
    for (int tt = 0; tt < 32; ++tt) acc[tt] = be2;
    for (int kc = 0; kc < 4; ++kc) {
        float wreg[32];
        #pragma unroll
        for (int i2 = 0; i2 < 32; ++i2) wreg[i2] = W_e2[(kc * 32 + i2) * H_ + j];
        #pragma unroll
        for (int tt = 0; tt < 32; ++tt) {
            int t = th * 32 + tt;
            const float4* hrow = (const float4*)(&h1[t * H_ + kc * 32]);
            float s = 0.f;
            #pragma unroll
            for (int w4 = 0; w4 < 8; ++w4) {
                float4 hv = hrow[w4];
                s += hv.x * wreg[w4 * 4 + 0] + hv.y * wreg[w4 * 4 + 1] +
                     hv.z * wreg[w4 * 4 + 2] + hv.w * wreg[w4 * 4 + 3];
            }
            acc[tt] += s;
        }
    }
    float msum = 0.f;
    #pragma unroll
    for (int tt = 0; tt < 32; ++tt) msum += silu_f(acc[tt]);
    hps[th * H_ + j] = msum;
    __syncthreads();
    if (tid < H_) hp[tid] = (hps[tid] + hps[H_ + tid]) * (1.f / 64.f);
    __syncthreads();

    {
        const float* Wm = (th == 0) ? W_mu : W_sig;
        float a = 0.f;
        #pragma unroll 4
        for (int k = 0; k < H_; ++k) a += hp[k] * Wm[k * H_ + j];
        if (th == 0) muS[j] = a; else sgS[j] = a;
    }
    __syncthreads();
    if (tid < H_) {
        float sig = 0.1f + 0.9f / (1.f + __expf(-sgS[tid]));
        float v = muS[tid] + sig * eps[(size_t)br * H_ + tid];
        vS[tid] = v;
        if (tid < L_) Lz[(size_t)br * L_ + tid] = v;
        else          Dz[(size_t)br * D_ + (tid - L_)] = v;
    }
    __syncthreads();
    if (tid < L_) {
        float a = 0.f;
        #pragma unroll 4
        for (int k = 0; k < D_; ++k) a += vS[L_ + k] * W_dyn[k * L_ + tid];
        dynb[(size_t)br * L_ + tid] = a;
    }
}

// ---------------------------------------------------------------------------
// ode (MFMA): one block per batch, 8 waves. R6's proven loop (2 barriers/stage,
// weights in LDS, burst x-prefetch, 3 chains in phase 2) + R7's CSR fold.
// ---------------------------------------------------------------------------
__global__ __launch_bounds__(512, 2) void ode_kernel(
    const float* __restrict__ Lz, const float* __restrict__ dynb,
    const float* __restrict__ W_msg, const float* __restrict__ W_self,
    const float* __restrict__ b_ode,
    const int* __restrict__ src, const int* __restrict__ dst,
    const float* __restrict__ space_w,
    float* __restrict__ traj) {
    const int b = blockIdx.x;
    const int tid = threadIdx.x;
    const int lane = tid & 63;
    const int w = tid >> 6;          // 0..7
    const int rb = w & 3;            // output row block (32 rows)
    const int cb = w >> 2;           // output col block (32 cols)
    const int l31 = lane & 31;
    const int h = lane >> 5;
    const int cc = cb * 32 + l31;    // this thread's output column (0..63)

    extern __shared__ char sm[];
    float* Af = (float*)sm;                    // fp32 A staging [128][128]
    int* permS = (int*)(sm + PRM_OFF);         // 2048
    int* cntS  = permS + ES_;                  // 128
    int* rsS   = cntS + R_;                    // 129

    // ---- static weights -> LDS (hi/lo, transposed: WT[j][s][k] = W[k][j]) ----
    for (int idx = tid; idx < 4096; idx += 512) {
        int j = idx & 63, k = idx >> 6;
        float vs = W_self[k * 64 + j];
        f16 sh = (f16)vs;
        *(f16*)(sm + WS_OFF + swz256(j, 0, k * 2)) = sh;
        *(f16*)(sm + WS_OFF + swz256(j, 1, k * 2)) = (f16)(vs - (float)sh);
        float vm = W_msg[k * 64 + j];
        f16 mh = (f16)vm;
        *(f16*)(sm + WM_OFF + swz256(j, 0, k * 2)) = mh;
        *(f16*)(sm + WM_OFF + swz256(j, 1, k * 2)) = (f16)(vm - (float)mh);
    }
    // ---- CSR build (deterministic, per-block; folded prep) ----
    if (tid < R_) {
        int c = 0;
        for (int e = 0; e < ES_; ++e) c += (dst[e] == tid) ? 1 : 0;
        cntS[tid] = c;
    }
    __syncthreads();
    if (tid == 0) {
        int a = 0;
        for (int i = 0; i < R_; ++i) { rsS[i] = a; a += cntS[i]; }
        rsS[R_] = a;
    }
    __syncthreads();
    if (tid < R_) {
        int k = rsS[tid];
        for (int e = 0; e < ES_; ++e)
            if (dst[e] == tid) permS[k++] = e;
    }
    for (int i = tid; i < 128 * 128; i += 512) Af[i] = 0.f;
    __syncthreads();
    if (tid < R_) {
        int e0_ = rsS[tid], e1_ = rsS[tid + 1];
        for (int e = e0_; e < e1_; ++e) {
            int pe = permS[e];
            Af[tid * 128 + src[pe]] += space_w[b * ES_ + pe];
        }
    }
    __syncthreads();

    // ---- A fragments -> VGPRs (hi/lo) ----
    f16x8 aH[8], aL[8];
    {
        int row = rb * 32 + l31;
        #pragma unroll
        for (int m = 0; m < 8; ++m) {
            const float* p = Af + row * 128 + m * 16 + h * 8;
            f16x8 vh, vl;
            #pragma unroll
            for (int i = 0; i < 8; ++i) {
                float v = p[i];
                f16 hi = (f16)v;
                vh[i] = hi;
                vl[i] = (f16)(v - (float)hi);
            }
            aH[m] = vh;
            aL[m] = vl;
        }
    }

    // ---- per-thread state in C-layout ----
    float xb[16], ks[16], dnb[16];
    {
        float bo = b_ode[cc];
        #pragma unroll
        for (int i = 0; i < 16; ++i) {
            int r = rb * 32 + (i & 3) + 8 * (i >> 2) + 4 * h;
            size_t o = ((size_t)(b * R_ + r)) * L_ + cc;
            xb[i] = Lz[o];
            dnb[i] = dynb[o] + bo;
        }
    }
    __syncthreads();  // Af dead; LDS 0..64KB becomes XROW+MT

    // ---- write initial x (hi/lo planes) ----
    #pragma unroll
    for (int i = 0; i < 16; ++i) {
        int r = rb * 32 + (i & 3) + 8 * (i >> 2) + 4 * h;
        f16 hi = (f16)xb[i];
        *(f16*)(sm + XROW_OFF + swz256(r, 0, cc * 2)) = hi;
        *(f16*)(sm + XROW_OFF + swz256(r, 1, cc * 2)) = (f16)(xb[i] - (float)hi);
    }
    __syncthreads();

    const int rowx = rb * 32 + l31;   // A-operand row for this lane

    for (int n = 0; n < T_; ++n) {
        #pragma unroll
        for (int i = 0; i < 16; ++i) ks[i] = 0.f;
        for (int s4 = 0; s4 < 4; ++s4) {
            const float wk = (s4 == 1 || s4 == 2) ? 2.f : 1.f;
            const float cn = (s4 < 2) ? 0.05f : 0.1f;

            // ===== phase 1: S = dyn + x@Wself, M = x@Wmsg =====
            // burst-prefetch all x fragments (8 b128)
            f16x8 xh[4], xl[4];
            #pragma unroll
            for (int m = 0; m < 4; ++m) {
                uint32_t kB = (m * 16 + 8 * h) * 2;
                xh[m] = *(const f16x8*)(sm + XROW_OFF + swz256(rowx, 0, kB));
                xl[m] = *(const f16x8*)(sm + XROW_OFF + swz256(rowx, 1, kB));
            }
            f32x16 aS, aM = {};
            #pragma unroll
            for (int i = 0; i < 16; ++i) aS[i] = dnb[i];
            #pragma unroll
            for (int m = 0; m < 4; ++m) {
                uint32_t kB = (m * 16 + 8 * h) * 2;
                f16x8 wsH = *(const f16x8*)(sm + WS_OFF + swz256(cc, 0, kB));
                f16x8 wsL = *(const f16x8*)(sm + WS_OFF + swz256(cc, 1, kB));
                f16x8 wmH = *(const f16x8*)(sm + WM_OFF + swz256(cc, 0, kB));
                f16x8 wmL = *(const f16x8*)(sm + WM_OFF + swz256(cc, 1, kB));
                aS = __builtin_amdgcn_mfma_f32_32x32x16_f16(xh[m], wsH, aS, 0, 0, 0);
                aM = __builtin_amdgcn_mfma_f32_32x32x16_f16(xh[m], wmH, aM, 0, 0, 0);
                aS = __builtin_amdgcn_mfma_f32_32x32x16_f16(xl[m], wsH, aS, 0, 0, 0);
                aM = __builtin_amdgcn_mfma_f32_32x32x16_f16(xl[m], wmH, aM, 0, 0, 0);
                aS = __builtin_amdgcn_mfma_f32_32x32x16_f16(xh[m], wsL, aS, 0, 0, 0);
                aM = __builtin_amdgcn_mfma_f32_32x32x16_f16(xh[m], wmL, aM, 0, 0, 0);
            }
            // write M^T hi/lo (rows 4q consecutive per b64)
            #pragma unroll
            for (int q = 0; q < 4; ++q) {
                int rbase = rb * 32 + 8 * q + 4 * h;
                f16x4 vh, vl;
                #pragma unroll
                for (int u = 0; u < 4; ++u) {
                    float t = aM[4 * q + u];
                    f16 hi = (f16)t;
                    vh[u] = hi;
                    vl[u] = (f16)(t - (float)hi);
                }
                *(f16x4*)(sm + MT_OFF + swzT(cc, 0, rbase * 2)) = vh;
                *(f16x4*)(sm + MT_OFF + swzT(cc, 1, rbase * 2)) = vl;
            }
            __syncthreads();

            // ===== phase 2: accK = S + A@M (3 independent chains) =====
            f32x16 e0 = {}, e1 = {}, e2 = {};
            #pragma unroll
            for (int m = 0; m < 8; ++m) {
                f16x8 mtH = *(const f16x8*)(sm + MT_OFF + swzT(cc, 0, (m * 16 + 8 * h) * 2));
                f16x8 mtL = *(const f16x8*)(sm + MT_OFF + swzT(cc, 1, (m * 16 + 8 * h) * 2));
                if (m < 3) {
                    e0 = __builtin_amdgcn_mfma_f32_32x32x16_f16(aH[m], mtH, e0, 0, 0, 0);
                    e0 = __builtin_amdgcn_mfma_f32_32x32x16_f16(aL[m], mtH, e0, 0, 0, 0);
                    e0 = __builtin_amdgcn_mfma_f32_32x32x16_f16(aH[m], mtL, e0, 0, 0, 0);
                } else if (m < 6) {
                    e1 = __builtin_amdgcn_mfma_f32_32x32x16_f16(aH[m], mtH, e1, 0, 0, 0);
                    e1 = __builtin_amdgcn_mfma_f32_32x32x16_f16(aL[m], mtH, e1, 0, 0, 0);
                    e1 = __builtin_amdgcn_mfma_f32_32x32x16_f16(aH[m], mtL, e1, 0, 0, 0);
                } else {
                    e2 = __builtin_amdgcn_mfma_f32_32x32x16_f16(aH[m], mtH, e2, 0, 0, 0);
                    e2 = __builtin_amdgcn_mfma_f32_32x32x16_f16(aL[m], mtH, e2, 0, 0, 0);
                    e2 = __builtin_amdgcn_mfma_f32_32x32x16_f16(aH[m], mtL, e2, 0, 0, 0);
                }
            }
            // epilogue: tanh, RK4, write x hi/lo planes
            float xn_[16];
            #pragma unroll
            for (int i = 0; i < 16; ++i) {
                float kv = tanh_f(aS[i] + e0[i] + e1[i] + e2[i]);
                ks[i] += wk * kv;
                xn_[i] = (s4 < 3) ? (xb[i] + cn * kv) : (xb[i] + (0.1f / 6.f) * ks[i]);
            }
            if (s4 == 3) {
                #pragma unroll
                for (int i = 0; i < 16; ++i) xb[i] = xn_[i];
            }
            #pragma unroll
            for (int i = 0; i < 16; ++i) {
                int r = rb * 32 + (i & 3) + 8 * (i >> 2) + 4 * h;
                f16 hi = (f16)xn_[i];
                *(f16*)(sm + XROW_OFF + swz256(r, 0, cc * 2)) = hi;
                *(f16*)(sm + XROW_OFF + swz256(r, 1, cc * 2)) = (f16)(xn_[i] - (float)hi);
            }
            if (s4 == 3) {
                #pragma unroll
                for (int i = 0; i < 16; ++i) {
                    int r = rb * 32 + (i & 3) + 8 * (i >> 2) + 4 * h;
                    traj[(((size_t)b * T_ + n) * R_ + r) * L_ + cc] = xb[i];
                }
            }
            __syncthreads();
        }
    }
}

// ---------------------------------------------------------------------------
// decoder: one block per (b,r), one-hot rid exploited as row lookup.
// ---------------------------------------------------------------------------
__global__ __launch_bounds__(256) void decoder_kernel(
    const float* __restrict__ traj, const float* __restrict__ Dz,
    const float* __restrict__ W_d1, const float* __restrict__ b_d1,
    const float* __restrict__ W_d2, const float* __restrict__ b_d2,
    float* __restrict__ y) {
    int br = blockIdx.x;
    int b = br >> 7;
    int r = br & 127;
    int tid = threadIdx.x;
    __shared__ __align__(16) float trajS[32 * L_];
    __shared__ __align__(16) float hS[32 * H_];
    __shared__ float dzS[D_];
    __shared__ float baseS[H_];

    int j = tid & 127;
    int th = tid >> 7;
    if (tid < D_) dzS[tid] = Dz[(size_t)br * D_ + tid];
    __syncthreads();

    float wcol[64];
    #pragma unroll
    for (int k = 0; k < 64; ++k) wcol[k] = W_d1[k * H_ + j];
    float wt = W_d1[128 * H_ + j];
    if (th == 0) {
        float a = b_d1[j] + W_d1[(129 + r) * H_ + j];
        #pragma unroll 4
        for (int k = 0; k < D_; ++k) a += dzS[k] * W_d1[(64 + k) * H_ + j];
        baseS[j] = a;
    }
    __syncthreads();
    float bb = baseS[j];

    for (int half = 0; half < 2; ++half) {
        for (int i = tid; i < 32 * L_; i += 256) {
            int tt = i >> 6, l = i & 63;
            trajS[i] = traj[(((size_t)b * T_ + half * 32 + tt) * R_ + r) * L_ + l];
        }
        __syncthreads();
        #pragma unroll
        for (int tt = 0; tt < 16; ++tt) {
            int tl = th * 16 + tt;
            int t = half * 32 + tl;
            float a = bb + (float)t * (1.f / 64.f) * wt;
            const float4* tr4 = (const float4*)(&trajS[tl * L_]);
            #pragma unroll
            for (int kb = 0; kb < 16; ++kb) {
                float4 tv = tr4[kb];
                a += tv.x * wcol[kb * 4 + 0] + tv.y * wcol[kb * 4 + 1] +
                     tv.z * wcol[kb * 4 + 2] + tv.w * wcol[kb * 4 + 3];
            }
            hS[tl * H_ + j] = silu_f(a);
        }
        __syncthreads();
        {
            int o = tid & 31, q = tid >> 5;
            float acc2[4];
            float bd2 = b_d2[o];
            #pragma unroll
            for (int u = 0; u < 4; ++u) acc2[u] = bd2;
            for (int jc = 0; jc < 4; ++jc) {
                float wreg[32];
                #pragma unroll
                for (int i2 = 0; i2 < 32; ++i2) wreg[i2] = W_d2[(jc * 32 + i2) * OUT_ + o];
                #pragma unroll
                for (int u = 0; u < 4; ++u) {
                    int tl = q * 4 + u;
                    const float4* h4 = (const float4*)(&hS[tl * H_ + jc * 32]);
                    float s2 = 0.f;
                    #pragma unroll
                    for (int w4 = 0; w4 < 8; ++w4) {
                        float4 hv = h4[w4];
                        s2 += hv.x * wreg[w4 * 4 + 0] + hv.y * wreg[w4 * 4 + 1] +
                              hv.z * wreg[w4 * 4 + 2] + hv.w * wreg[w4 * 4 + 3];
                    }
                    acc2[u] += s2;
                }
            }
            #pragma unroll
            for (int u = 0; u < 4; ++u) {
                int t = half * 32 + q * 4 + u;
                y[((size_t)br * T_ + t) * OUT_ + o] = acc2[u];
            }
        }
        __syncthreads();
    }
}

extern "C" void kernel_launch(void* const* d_in, const int* in_sizes, int n_in,
                              void* d_out, int out_size, void* d_ws, size_t ws_size,
                              hipStream_t stream) {
    const float* node_feats = (const float*)d_in[0];
    const float* eps_       = (const float*)d_in[1];
    const float* space_w    = (const float*)d_in[2];
    const int*   src        = (const int*)d_in[3];
    const int*   dst        = (const int*)d_in[4];
    const float* W_e1 = (const float*)d_in[5];
    const float* b_e1 = (const float*)d_in[6];
    const float* W_e2 = (const float*)d_in[7];
    const float* b_e2 = (const float*)d_in[8];
    const float* W_mu = (const float*)d_in[9];
    const float* W_sig = (const float*)d_in[10];
    const float* W_msg = (const float*)d_in[11];
    const float* W_self = (const float*)d_in[12];
    const float* W_dyn = (const float*)d_in[13];
    const float* b_ode = (const float*)d_in[14];
    const float* W_d1 = (const float*)d_in[15];
    const float* b_d1 = (const float*)d_in[16];
    const float* W_d2 = (const float*)d_in[17];
    const float* b_d2 = (const float*)d_in[18];
    float* out = (float*)d_out;

    float* f_ws = (float*)d_ws;
    float* Lz    = f_ws;                              // 65536
    float* Dz    = Lz + B_ * R_ * L_;                 // 65536
    float* dynb  = Dz + B_ * R_ * D_;                 // 65536
    float* traj  = dynb + B_ * R_ * L_;               // 4194304

    encoder_kernel<<<B_ * R_, 256, 0, stream>>>(node_feats, eps_, W_e1, b_e1, W_e2, b_e2,
                                                W_mu, W_sig, W_dyn, Lz, Dz, dynb);
    ode_kernel<<<B_, 512, ODE_LDS, stream>>>(Lz, dynb, W_msg, W_self, b_ode,
                                             src, dst, space_w, traj);
    decoder_kernel<<<B_ * R_, 256, 0, stream>>>(traj, Dz, W_d1, b_d1, W_d2, b_d2, out);
}

// Round 10
// 1448.755 us; speedup vs baseline: 2.0663x; 1.1289x over previous
//
#include <hip/hip_runtime.h>

#define B_ 8
#define R_ 128
#define T_ 64
#define FIN_ 32
#define L_ 64
#define D_ 64
#define H_ 128
#define OUT_ 32
#define ES_ 2048

typedef _Float16 f16;
typedef __attribute__((ext_vector_type(2))) _Float16 f16x2;
typedef __attribute__((ext_vector_type(4))) _Float16 f16x4;
typedef __attribute__((ext_vector_type(8))) _Float16 f16x8;
typedef __attribute__((ext_vector_type(16))) float f32x16;

__device__ __forceinline__ float silu_f(float x) { return x / (1.f + __expf(-x)); }
__device__ __forceinline__ float tanh_f(float x) {
    float e = __expf(2.f * x);
    return 1.f - 2.f / (e + 1.f);
}

// packed x: [128 r][64 c] dwords (hi f16 | lo f16 << 16), 256B row stride.
__device__ __forceinline__ uint32_t swzP(uint32_t r, uint32_t cByte) {
    return (r * 256u + cByte) ^ ((r & 15u) << 4);
}
// 256B-stride hi/lo-interleaved arrays (weights): XOR row into 16B-granule bits.
__device__ __forceinline__ uint32_t swz256(uint32_t row, uint32_t s, uint32_t colByte) {
    uint32_t bo = row * 256u + s * 128u + colByte;
    return bo ^ ((row & 15u) << 4);
}
// M^T: [64 c][2 s][128 r] f16, 512B rows.
__device__ __forceinline__ uint32_t swzT(uint32_t c, uint32_t s, uint32_t rByte) {
    uint32_t bo = c * 512u + s * 256u + rByte;
    return bo ^ ((c & 31u) << 4);
}

__device__ __forceinline__ uint32_t pack2_f16(f16 a, f16 b) {
    union { f16x2 h; uint32_t u; } r;
    r.h[0] = a; r.h[1] = b;
    return r.u;
}

#define XP_OFF   0u       // 32 KB packed x [128 r][64 c] dwords
#define MT_OFF   32768u   // 32 KB M^T     [64 c][2 s][128 r] f16
#define WS_OFF   65536u   // 16 KB Wself^T [64 j][2 s][64 k] f16
#define WM_OFF   81920u   // 16 KB Wmsg^T
#define PRM_OFF  98304u   // CSR scratch: permS[2048], cnt4[512], cntS[128], rsS[129]
#define ODE_LDS  110592u  // A staging (64 KB fp32) aliases XP+MT pre-loop

// ---------------------------------------------------------------------------
// encoder: one block per (b,r).  (R6 version, unchanged)
// ---------------------------------------------------------------------------
__global__ __launch_bounds__(256) void encoder_kernel(
    const float* __restrict__ node_feats, const float* __restrict__ eps,
    const float* __restrict__ W_e1, const float* __restrict__ b_e1,
    const float* __restrict__ W_e2, const float* __restrict__ b_e2,
    const float* __restrict__ W_mu, const float* __restrict__ W_sig,
    const float* __restrict__ W_dyn,
    float* __restrict__ Lz, float* __restrict__ Dz, float* __restrict__ dynb) {
    int br = blockIdx.x;
    int tid = threadIdx.x;
    __shared__ __align__(16) float xS[T_ * 36];
    __shared__ __align__(16) float h1[T_ * H_];
    __shared__ float hps[2 * H_];
    __shared__ float hp[H_];
    __shared__ float muS[H_], sgS[H_], vS[H_];

    const float* nf = node_feats + (size_t)br * (T_ * FIN_);
    for (int i = tid; i < T_ * FIN_; i += 256) {
        int t = i >> 5, f = i & 31;
        xS[t * 36 + f] = nf[i];
    }
    if (tid < T_) xS[tid * 36 + 32] = (float)tid * (1.f / 64.f);

    int j = tid & 127;
    int th = tid >> 7;
    float we1r[33];
    #pragma unroll
    for (int k = 0; k < 33; ++k) we1r[k] = W_e1[k * H_ + j];
    __syncthreads();

    float be1 = b_e1[j];
    for (int tt = 0; tt < 32; ++tt) {
        int t = th * 32 + tt;
        float a = be1;
        const float4* xr = (const float4*)(&xS[t * 36]);
        #pragma unroll
        for (int w4 = 0; w4 < 8; ++w4) {
            float4 xv = xr[w4];
            a += xv.x * we1r[w4 * 4 + 0] + xv.y * we1r[w4 * 4 + 1] +
                 xv.z * we1r[w4 * 4 + 2] + xv.w * we1r[w4 * 4 + 3];
        }
        a += xS[t * 36 + 32] * we1r[32];
        h1[t * H_ + j] = silu_f(a);
    }
    __syncthreads();

    float acc[32];
    float be2 = b_e2[j];
    #pragma unroll
    for (int tt = 0; tt < 32; ++tt) acc[tt] = be2;
    for (int kc = 0; kc < 4; ++kc) {
        float wreg[32];
        #pragma unroll
        for (int i2 = 0; i2 < 32; ++i2) wreg[i2] = W_e2[(kc * 32 + i2) * H_ + j];
        #pragma unroll
        for (int tt = 0; tt < 32; ++tt) {
            int t = th * 32 + tt;
            const float4* hrow = (const float4*)(&h1[t * H_ + kc * 32]);
            float s = 0.f;
            #pragma unroll
            for (int w4 = 0; w4 < 8; ++w4) {
                float4 hv = hrow[w4];
                s += hv.x * wreg[w4 * 4 + 0] + hv.y * wreg[w4 * 4 + 1] +
                     hv.z * wreg[w4 * 4 + 2] + hv.w * wreg[w4 * 4 + 3];
            }
            acc[tt] += s;
        }
    }
    float msum = 0.f;
    #pragma unroll
    for (int tt = 0; tt < 32; ++tt) msum += silu_f(acc[tt]);
    hps[th * H_ + j] = msum;
    __syncthreads();
    if (tid < H_) hp[tid] = (hps[tid] + hps[H_ + tid]) * (1.f / 64.f);
    __syncthreads();

    {
        const float* Wm = (th == 0) ? W_mu : W_sig;
        float a = 0.f;
        #pragma unroll 4
        for (int k = 0; k < H_; ++k) a += hp[k] * Wm[k * H_ + j];
        if (th == 0) muS[j] = a; else sgS[j] = a;
    }
    __syncthreads();
    if (tid < H_) {
        float sig = 0.1f + 0.9f / (1.f + __expf(-sgS[tid]));
        float v = muS[tid] + sig * eps[(size_t)br * H_ + tid];
        vS[tid] = v;
        if (tid < L_) Lz[(size_t)br * L_ + tid] = v;
        else          Dz[(size_t)br * D_ + (tid - L_)] = v;
    }
    __syncthreads();
    if (tid < L_) {
        float a = 0.f;
        #pragma unroll 4
        for (int k = 0; k < D_; ++k) a += vS[L_ + k] * W_dyn[k * L_ + tid];
        dynb[(size_t)br * L_ + tid] = a;
    }
}

// ---------------------------------------------------------------------------
// ode (MFMA): one block per batch, 8 waves. R6's proven loop (2 barriers/stage,
// weights in LDS, burst x-prefetch, 3 chains in phase 2) with:
//   - CSR build parallelized 4x (4 edge-chunks x 128 rows over 512 threads)
//   - x stored packed (hi|lo per dword): 16 b32 epilogue writes, v_perm unpack
// ---------------------------------------------------------------------------
__global__ __launch_bounds__(512, 2) void ode_kernel(
    const float* __restrict__ Lz, const float* __restrict__ dynb,
    const float* __restrict__ W_msg, const float* __restrict__ W_self,
    const float* __restrict__ b_ode,
    const int* __restrict__ src, const int* __restrict__ dst,
    const float* __restrict__ space_w,
    float* __restrict__ traj) {
    const int b = blockIdx.x;
    const int tid = threadIdx.x;
    const int lane = tid & 63;
    const int w = tid >> 6;          // 0..7
    const int rb = w & 3;            // output row block (32 rows)
    const int cb = w >> 2;           // output col block (32 cols)
    const int l31 = lane & 31;
    const int h = lane >> 5;
    const int cc = cb * 32 + l31;    // this thread's output column (0..63)

    extern __shared__ char sm[];
    float* Af  = (float*)sm;                   // fp32 A staging [128][128]
    int* permS = (int*)(sm + PRM_OFF);         // 2048
    int* cnt4  = permS + ES_;                  // 512  (4 chunks x 128 rows)
    int* cntS  = cnt4 + 512;                   // 128
    int* rsS   = cntS + R_;                    // 129

    // ---- static weights -> LDS (hi/lo, transposed: WT[j][s][k] = W[k][j]) ----
    for (int idx = tid; idx < 4096; idx += 512) {
        int j = idx & 63, k = idx >> 6;
        float vs = W_self[k * 64 + j];
        f16 sh = (f16)vs;
        *(f16*)(sm + WS_OFF + swz256(j, 0, k * 2)) = sh;
        *(f16*)(sm + WS_OFF + swz256(j, 1, k * 2)) = (f16)(vs - (float)sh);
        float vm = W_msg[k * 64 + j];
        f16 mh = (f16)vm;
        *(f16*)(sm + WM_OFF + swz256(j, 0, k * 2)) = mh;
        *(f16*)(sm + WM_OFF + swz256(j, 1, k * 2)) = (f16)(vm - (float)mh);
    }

    // ---- CSR build, 4-way parallel (stable: chunks are consecutive ranges) ----
    {
        const int c4 = tid >> 7;          // chunk 0..3 (512 edges each)
        const int rr = tid & 127;
        int c = 0;
        const int eb = c4 * 512;
        for (int e = eb; e < eb + 512; ++e) c += (dst[e] == rr) ? 1 : 0;
        cnt4[c4 * 128 + rr] = c;
    }
    __syncthreads();
    if (tid < R_)
        cntS[tid] = cnt4[tid] + cnt4[128 + tid] + cnt4[256 + tid] + cnt4[384 + tid];
    __syncthreads();
    if (tid == 0) {
        int a = 0;
        for (int i = 0; i < R_; ++i) { rsS[i] = a; a += cntS[i]; }
        rsS[R_] = a;
    }
    __syncthreads();
    {
        const int c4 = tid >> 7;
        const int rr = tid & 127;
        int k = rsS[rr];
        for (int c = 0; c < c4; ++c) k += cnt4[c * 128 + rr];
        const int eb = c4 * 512;
        for (int e = eb; e < eb + 512; ++e)
            if (dst[e] == rr) permS[k++] = e;
    }
    for (int i = tid; i < 128 * 128; i += 512) Af[i] = 0.f;
    __syncthreads();
    if (tid < R_) {
        int e0_ = rsS[tid], e1_ = rsS[tid + 1];
        for (int e = e0_; e < e1_; ++e) {
            int pe = permS[e];
            Af[tid * 128 + src[pe]] += space_w[b * ES_ + pe];
        }
    }
    __syncthreads();

    // ---- A fragments -> VGPRs (hi/lo) ----
    f16x8 aH[8], aL[8];
    {
        int row = rb * 32 + l31;
        #pragma unroll
        for (int m = 0; m < 8; ++m) {
            const float* p = Af + row * 128 + m * 16 + h * 8;
            f16x8 vh, vl;
            #pragma unroll
            for (int i = 0; i < 8; ++i) {
                float v = p[i];
                f16 hi = (f16)v;
                vh[i] = hi;
                vl[i] = (f16)(v - (float)hi);
            }
            aH[m] = vh;
            aL[m] = vl;
        }
    }

    // ---- per-thread state in C-layout ----
    float xb[16], ks[16], dnb[16];
    {
        float bo = b_ode[cc];
        #pragma unroll
        for (int i = 0; i < 16; ++i) {
            int r = rb * 32 + (i & 3) + 8 * (i >> 2) + 4 * h;
            size_t o = ((size_t)(b * R_ + r)) * L_ + cc;
            xb[i] = Lz[o];
            dnb[i] = dynb[o] + bo;
        }
    }
    __syncthreads();  // Af dead; LDS 0..64KB becomes XP+MT

    // ---- write initial packed x ----
    #pragma unroll
    for (int i = 0; i < 16; ++i) {
        int r = rb * 32 + (i & 3) + 8 * (i >> 2) + 4 * h;
        f16 hi = (f16)xb[i];
        *(uint32_t*)(sm + XP_OFF + swzP(r, (uint32_t)cc * 4u)) =
            pack2_f16(hi, (f16)(xb[i] - (float)hi));
    }
    __syncthreads();

    const int rowx = rb * 32 + l31;   // A-operand row for this lane

    for (int n = 0; n < T_; ++n) {
        #pragma unroll
        for (int i = 0; i < 16; ++i) ks[i] = 0.f;
        for (int s4 = 0; s4 < 4; ++s4) {
            const float wk = (s4 == 1 || s4 == 2) ? 2.f : 1.f;
            const float cn = (s4 < 2) ? 0.05f : 0.1f;

            // ===== phase 1: S = dyn + x@Wself, M = x@Wmsg =====
            // burst-prefetch all x (8 b128 packed), unpack hi/lo via v_perm
            f16x8 xh[4], xl[4];
            #pragma unroll
            for (int m = 0; m < 4; ++m) {
                uint32_t cB = (uint32_t)(m * 16 + 8 * h) * 4u;
                uint4 p0 = *(const uint4*)(sm + XP_OFF + swzP(rowx, cB));
                uint4 p1 = *(const uint4*)(sm + XP_OFF + swzP(rowx, cB + 16u));
                union { uint32_t u[4]; f16x8 v; } H, L;
                H.u[0] = __builtin_amdgcn_perm(p0.y, p0.x, 0x05040100u);
                H.u[1] = __builtin_amdgcn_perm(p0.w, p0.z, 0x05040100u);
                H.u[2] = __builtin_amdgcn_perm(p1.y, p1.x, 0x05040100u);
                H.u[3] = __builtin_amdgcn_perm(p1.w, p1.z, 0x05040100u);
                L.u[0] = __builtin_amdgcn_perm(p0.y, p0.x, 0x07060302u);
                L.u[1] = __builtin_amdgcn_perm(p0.w, p0.z, 0x07060302u);
                L.u[2] = __builtin_amdgcn_perm(p1.y, p1.x, 0x07060302u);
                L.u[3] = __builtin_amdgcn_perm(p1.w, p1.z, 0x07060302u);
                xh[m] = H.v; xl[m] = L.v;
            }
            f32x16 aS, aM = {};
            #pragma unroll
            for (int i = 0; i < 16; ++i) aS[i] = dnb[i];
            #pragma unroll
            for (int m = 0; m < 4; ++m) {
                uint32_t kB = (m * 16 + 8 * h) * 2;
                f16x8 wsH = *(const f16x8*)(sm + WS_OFF + swz256(cc, 0, kB));
                f16x8 wsL = *(const f16x8*)(sm + WS_OFF + swz256(cc, 1, kB));
                f16x8 wmH = *(const f16x8*)(sm + WM_OFF + swz256(cc, 0, kB));
                f16x8 wmL = *(const f16x8*)(sm + WM_OFF + swz256(cc, 1, kB));
                aS = __builtin_amdgcn_mfma_f32_32x32x16_f16(xh[m], wsH, aS, 0, 0, 0);
                aM = __builtin_amdgcn_mfma_f32_32x32x16_f16(xh[m], wmH, aM, 0, 0, 0);
                aS = __builtin_amdgcn_mfma_f32_32x32x16_f16(xl[m], wsH, aS, 0, 0, 0);
                aM = __builtin_amdgcn_mfma_f32_32x32x16_f16(xl[m], wmH, aM, 0, 0, 0);
                aS = __builtin_amdgcn_mfma_f32_32x32x16_f16(xh[m], wsL, aS, 0, 0, 0);
                aM = __builtin_amdgcn_mfma_f32_32x32x16_f16(xh[m], wmL, aM, 0, 0, 0);
            }
            // write M^T hi/lo (rows 4q consecutive per b64)
            #pragma unroll
            for (int q = 0; q < 4; ++q) {
                int rbase = rb * 32 + 8 * q + 4 * h;
                f16x4 vh, vl;
                #pragma unroll
                for (int u = 0; u < 4; ++u) {
                    float t = aM[4 * q + u];
                    f16 hi = (f16)t;
                    vh[u] = hi;
                    vl[u] = (f16)(t - (float)hi);
                }
                *(f16x4*)(sm + MT_OFF + swzT(cc, 0, rbase * 2)) = vh;
                *(f16x4*)(sm + MT_OFF + swzT(cc, 1, rbase * 2)) = vl;
            }
            __syncthreads();

            // ===== phase 2: accK = S + A@M (3 independent chains) =====
            f32x16 e0 = {}, e1 = {}, e2 = {};
            #pragma unroll
            for (int m = 0; m < 8; ++m) {
                f16x8 mtH = *(const f16x8*)(sm + MT_OFF + swzT(cc, 0, (m * 16 + 8 * h) * 2));
                f16x8 mtL = *(const f16x8*)(sm + MT_OFF + swzT(cc, 1, (m * 16 + 8 * h) * 2));
                if (m < 3) {
                    e0 = __builtin_amdgcn_mfma_f32_32x32x16_f16(aH[m], mtH, e0, 0, 0, 0);
                    e0 = __builtin_amdgcn_mfma_f32_32x32x16_f16(aL[m], mtH, e0, 0, 0, 0);
                    e0 = __builtin_amdgcn_mfma_f32_32x32x16_f16(aH[m], mtL, e0, 0, 0, 0);
                } else if (m < 6) {
                    e1 = __builtin_amdgcn_mfma_f32_32x32x16_f16(aH[m], mtH, e1, 0, 0, 0);
                    e1 = __builtin_amdgcn_mfma_f32_32x32x16_f16(aL[m], mtH, e1, 0, 0, 0);
                    e1 = __builtin_amdgcn_mfma_f32_32x32x16_f16(aH[m], mtL, e1, 0, 0, 0);
                } else {
                    e2 = __builtin_amdgcn_mfma_f32_32x32x16_f16(aH[m], mtH, e2, 0, 0, 0);
                    e2 = __builtin_amdgcn_mfma_f32_32x32x16_f16(aL[m], mtH, e2, 0, 0, 0);
                    e2 = __builtin_amdgcn_mfma_f32_32x32x16_f16(aH[m], mtL, e2, 0, 0, 0);
                }
            }
            // epilogue: tanh, RK4, write packed x
            float xn_[16];
            #pragma unroll
            for (int i = 0; i < 16; ++i) {
                float kv = tanh_f(aS[i] + e0[i] + e1[i] + e2[i]);
                ks[i] += wk * kv;
                xn_[i] = (s4 < 3) ? (xb[i] + cn * kv) : (xb[i] + (0.1f / 6.f) * ks[i]);
            }
            if (s4 == 3) {
                #pragma unroll
                for (int i = 0; i < 16; ++i) xb[i] = xn_[i];
            }
            #pragma unroll
            for (int i = 0; i < 16; ++i) {
                int r = rb * 32 + (i & 3) + 8 * (i >> 2) + 4 * h;
                f16 hi = (f16)xn_[i];
                *(uint32_t*)(sm + XP_OFF + swzP(r, (uint32_t)cc * 4u)) =
                    pack2_f16(hi, (f16)(xn_[i] - (float)hi));
            }
            if (s4 == 3) {
                #pragma unroll
                for (int i = 0; i < 16; ++i) {
                    int r = rb * 32 + (i & 3) + 8 * (i >> 2) + 4 * h;
                    traj[(((size_t)b * T_ + n) * R_ + r) * L_ + cc] = xb[i];
                }
            }
            __syncthreads();
        }
    }
}

// ---------------------------------------------------------------------------
// decoder: one block per (b,r), one-hot rid exploited as row lookup.
// ---------------------------------------------------------------------------
__global__ __launch_bounds__(256) void decoder_kernel(
    const float* __restrict__ traj, const float* __restrict__ Dz,
    const float* __restrict__ W_d1, const float* __restrict__ b_d1,
    const float* __restrict__ W_d2, const float* __restrict__ b_d2,
    float* __restrict__ y) {
    int br = blockIdx.x;
    int b = br >> 7;
    int r = br & 127;
    int tid = threadIdx.x;
    __shared__ __align__(16) float trajS[32 * L_];
    __shared__ __align__(16) float hS[32 * H_];
    __shared__ float dzS[D_];
    __shared__ float baseS[H_];

    int j = tid & 127;
    int th = tid >> 7;
    if (tid < D_) dzS[tid] = Dz[(size_t)br * D_ + tid];
    __syncthreads();

    float wcol[64];
    #pragma unroll
    for (int k = 0; k < 64; ++k) wcol[k] = W_d1[k * H_ + j];
    float wt = W_d1[128 * H_ + j];
    if (th == 0) {
        float a = b_d1[j] + W_d1[(129 + r) * H_ + j];
        #pragma unroll 4
        for (int k = 0; k < D_; ++k) a += dzS[k] * W_d1[(64 + k) * H_ + j];
        baseS[j] = a;
    }
    __syncthreads();
    float bb = baseS[j];

    for (int half = 0; half < 2; ++half) {
        for (int i = tid; i < 32 * L_; i += 256) {
            int tt = i >> 6, l = i & 63;
            trajS[i] = traj[(((size_t)b * T_ + half * 32 + tt) * R_ + r) * L_ + l];
        }
        __syncthreads();
        #pragma unroll
        for (int tt = 0; tt < 16; ++tt) {
            int tl = th * 16 + tt;
            int t = half * 32 + tl;
            float a = bb + (float)t * (1.f / 64.f) * wt;
            const float4* tr4 = (const float4*)(&trajS[tl * L_]);
            #pragma unroll
            for (int kb = 0; kb < 16; ++kb) {
                float4 tv = tr4[kb];
                a += tv.x * wcol[kb * 4 + 0] + tv.y * wcol[kb * 4 + 1] +
                     tv.z * wcol[kb * 4 + 2] + tv.w * wcol[kb * 4 + 3];
            }
            hS[tl * H_ + j] = silu_f(a);
        }
        __syncthreads();
        {
            int o = tid & 31, q = tid >> 5;
            float acc2[4];
            float bd2 = b_d2[o];
            #pragma unroll
            for (int u = 0; u < 4; ++u) acc2[u] = bd2;
            for (int jc = 0; jc < 4; ++jc) {
                float wreg[32];
                #pragma unroll
                for (int i2 = 0; i2 < 32; ++i2) wreg[i2] = W_d2[(jc * 32 + i2) * OUT_ + o];
                #pragma unroll
                for (int u = 0; u < 4; ++u) {
                    int tl = q * 4 + u;
                    const float4* h4 = (const float4*)(&hS[tl * H_ + jc * 32]);
                    float s2 = 0.f;
                    #pragma unroll
                    for (int w4 = 0; w4 < 8; ++w4) {
                        float4 hv = h4[w4];
                        s2 += hv.x * wreg[w4 * 4 + 0] + hv.y * wreg[w4 * 4 + 1] +
                              hv.z * wreg[w4 * 4 + 2] + hv.w * wreg[w4 * 4 + 3];
                    }
                    acc2[u] += s2;
                }
            }
            #pragma unroll
            for (int u = 0; u < 4; ++u) {
                int t = half * 32 + q * 4 + u;
                y[((size_t)br * T_ + t) * OUT_ + o] = acc2[u];
            }
        }
        __syncthreads();
    }
}

extern "C" void kernel_launch(void* const* d_in, const int* in_sizes, int n_in,
                              void* d_out, int out_size, void* d_ws, size_t ws_size,
                              hipStream_t stream) {
    const float* node_feats = (const float*)d_in[0];
    const float* eps_       = (const float*)d_in[1];
    const float* space_w    = (const float*)d_in[2];
    const int*   src        = (const int*)d_in[3];
    const int*   dst        = (const int*)d_in[4];
    const float* W_e1 = (const float*)d_in[5];
    const float* b_e1 = (const float*)d_in[6];
    const float* W_e2 = (const float*)d_in[7];
    const float* b_e2 = (const float*)d_in[8];
    const float* W_mu = (const float*)d_in[9];
    const float* W_sig = (const float*)d_in[10];
    const float* W_msg = (const float*)d_in[11];
    const float* W_self = (const float*)d_in[12];
    const float* W_dyn = (const float*)d_in[13];
    const float* b_ode = (const float*)d_in[14];
    const float* W_d1 = (const float*)d_in[15];
    const float* b_d1 = (const float*)d_in[16];
    const float* W_d2 = (const float*)d_in[17];
    const float* b_d2 = (const float*)d_in[18];
    float* out = (float*)d_out;

    float* f_ws = (float*)d_ws;
    float* Lz    = f_ws;                              // 65536
    float* Dz    = Lz + B_ * R_ * L_;                 // 65536
    float* dynb  = Dz + B_ * R_ * D_;                 // 65536
    float* traj  = dynb + B_ * R_ * L_;               // 4194304

    encoder_kernel<<<B_ * R_, 256, 0, stream>>>(node_feats, eps_, W_e1, b_e1, W_e2, b_e2,
                                                W_mu, W_sig, W_dyn, Lz, Dz, dynb);
    ode_kernel<<<B_, 512, ODE_LDS, stream>>>(Lz, dynb, W_msg, W_self, b_ode,
                                             src, dst, space_w, traj);
    decoder_kernel<<<B_ * R_, 256, 0, stream>>>(traj, Dz, W_d1, b_d1, W_d2, b_d2, out);
}

// Round 11
// 1421.168 us; speedup vs baseline: 2.1064x; 1.0194x over previous
//
#include <hip/hip_runtime.h>

#define B_ 8
#define R_ 128
#define T_ 64
#define FIN_ 32
#define L_ 64
#define D_ 64
#define H_ 128
#define OUT_ 32
#define ES_ 2048

typedef _Float16 f16;
typedef __attribute__((ext_vector_type(2))) _Float16 f16x2;
typedef __attribute__((ext_vector_type(4))) _Float16 f16x4;
typedef __attribute__((ext_vector_type(8))) _Float16 f16x8;
typedef __attribute__((ext_vector_type(16))) float f32x16;

__device__ __forceinline__ float silu_f(float x) { return x / (1.f + __expf(-x)); }
__device__ __forceinline__ float tanh_f(float x) {
    float e = __expf(2.f * x);
    return 1.f - 2.f / (e + 1.f);
}

// packed x: [128 r][64 c] dwords (hi f16 | lo f16 << 16), 256B row stride.
__device__ __forceinline__ uint32_t swzP(uint32_t r, uint32_t cByte) {
    return (r * 256u + cByte) ^ ((r & 15u) << 4);
}
// 256B-stride hi/lo-interleaved arrays (weights): XOR row into 16B-granule bits.
__device__ __forceinline__ uint32_t swz256(uint32_t row, uint32_t s, uint32_t colByte) {
    uint32_t bo = row * 256u + s * 128u + colByte;
    return bo ^ ((row & 15u) << 4);
}
// packed M^T: [64 c][128 r] dwords (hi|lo), 512B rows.
__device__ __forceinline__ uint32_t swzTP(uint32_t c, uint32_t rByte) {
    return (c * 512u + rByte) ^ ((c & 31u) << 4);
}

__device__ __forceinline__ uint32_t pack2_f16(f16 a, f16 b) {
    union { f16x2 h; uint32_t u; } r;
    r.h[0] = a; r.h[1] = b;
    return r.u;
}

#define XP_OFF   0u       // 32 KB packed x [128 r][64 c] dwords
#define MT_OFF   32768u   // 32 KB packed M^T [64 c][128 r] dwords
#define WS_OFF   65536u   // 16 KB Wself^T [64 j][2 s][64 k] f16
#define WM_OFF   81920u   // 16 KB Wmsg^T
#define PRM_OFF  98304u   // CSR scratch: permS[2048], cnt4[512], cntS[128], rsS[129]
#define ODE_LDS  110592u  // A staging (64 KB fp32) aliases XP+MT pre-loop

// ---------------------------------------------------------------------------
// encoder: one block per (b,r). Register-tiled (8t x 4j per thread) so h1/xS
// LDS rows are reused across 4 columns: DS instr/thread 1280 -> ~340.
// Weights read as coalesced float4 from global (L2-cached broadcast).
// ---------------------------------------------------------------------------
__global__ __launch_bounds__(256) void encoder_kernel(
    const float* __restrict__ node_feats, const float* __restrict__ eps,
    const float* __restrict__ W_e1, const float* __restrict__ b_e1,
    const float* __restrict__ W_e2, const float* __restrict__ b_e2,
    const float* __restrict__ W_mu, const float* __restrict__ W_sig,
    const float* __restrict__ W_dyn,
    float* __restrict__ Lz, float* __restrict__ Dz, float* __restrict__ dynb) {
    int br = blockIdx.x;
    int tid = threadIdx.x;
    __shared__ __align__(16) float xS[T_ * 36];
    __shared__ __align__(16) float h1[T_ * H_];
    __shared__ float hps2[8][H_];
    __shared__ float hp[H_];
    __shared__ float muS[H_], sgS[H_], vS[H_];

    const float* nf = node_feats + (size_t)br * (T_ * FIN_);
    for (int i = tid; i < T_ * FIN_; i += 256) {
        int t = i >> 5, f = i & 31;
        xS[t * 36 + f] = nf[i];
    }
    if (tid < T_) xS[tid * 36 + 32] = (float)tid * (1.f / 64.f);
    __syncthreads();

    const int jg = tid & 31;        // 32 column groups
    const int th8 = tid >> 5;       // 8 row groups
    const int j0 = jg * 4;
    const int t0 = th8 * 8;

    // ---- h1 = silu(x @ We1 + b1), 8t x 4j per thread ----
    float acc1[8][4];
    {
        float4 bv = *(const float4*)&b_e1[j0];
        #pragma unroll
        for (int t = 0; t < 8; ++t) {
            acc1[t][0] = bv.x; acc1[t][1] = bv.y; acc1[t][2] = bv.z; acc1[t][3] = bv.w;
        }
        #pragma unroll
        for (int kb = 0; kb < 4; ++kb) {
            const int k0 = kb * 8;
            float4 wr[8];
            #pragma unroll
            for (int i = 0; i < 8; ++i) wr[i] = *(const float4*)&W_e1[(k0 + i) * H_ + j0];
            #pragma unroll
            for (int t = 0; t < 8; ++t) {
                const float* xrow = &xS[(t0 + t) * 36 + k0];
                float4 xa = *(const float4*)xrow;
                float4 xc = *(const float4*)(xrow + 4);
                #pragma unroll
                for (int jj = 0; jj < 4; ++jj) {
                    float wj0 = (&wr[0].x)[jj], wj1 = (&wr[1].x)[jj], wj2 = (&wr[2].x)[jj], wj3 = (&wr[3].x)[jj];
                    float wj4 = (&wr[4].x)[jj], wj5 = (&wr[5].x)[jj], wj6 = (&wr[6].x)[jj], wj7 = (&wr[7].x)[jj];
                    acc1[t][jj] += xa.x * wj0 + xa.y * wj1 + xa.z * wj2 + xa.w * wj3 +
                                   xc.x * wj4 + xc.y * wj5 + xc.z * wj6 + xc.w * wj7;
                }
            }
        }
        float4 w32 = *(const float4*)&W_e1[32 * H_ + j0];
        #pragma unroll
        for (int t = 0; t < 8; ++t) {
            float xv = xS[(t0 + t) * 36 + 32];
            acc1[t][0] += xv * w32.x; acc1[t][1] += xv * w32.y;
            acc1[t][2] += xv * w32.z; acc1[t][3] += xv * w32.w;
        }
        #pragma unroll
        for (int t = 0; t < 8; ++t) {
            float4 o;
            o.x = silu_f(acc1[t][0]); o.y = silu_f(acc1[t][1]);
            o.z = silu_f(acc1[t][2]); o.w = silu_f(acc1[t][3]);
            *(float4*)&h1[(t0 + t) * H_ + j0] = o;
        }
    }
    __syncthreads();

    // ---- h2 = silu(h1 @ We2 + b2), 8t x 4j per thread; mean over t ----
    {
        float acc[8][4];
        float4 bv = *(const float4*)&b_e2[j0];
        #pragma unroll
        for (int t = 0; t < 8; ++t) {
            acc[t][0] = bv.x; acc[t][1] = bv.y; acc[t][2] = bv.z; acc[t][3] = bv.w;
        }
        for (int kb = 0; kb < 16; ++kb) {
            const int k0 = kb * 8;
            float4 wr[8];
            #pragma unroll
            for (int i = 0; i < 8; ++i) wr[i] = *(const float4*)&W_e2[(k0 + i) * H_ + j0];
            #pragma unroll
            for (int t = 0; t < 8; ++t) {
                const float4* hrow = (const float4*)&h1[(t0 + t) * H_ + k0];
                float4 ha = hrow[0];
                float4 hc = hrow[1];
                #pragma unroll
                for (int jj = 0; jj < 4; ++jj) {
                    float wj0 = (&wr[0].x)[jj], wj1 = (&wr[1].x)[jj], wj2 = (&wr[2].x)[jj], wj3 = (&wr[3].x)[jj];
                    float wj4 = (&wr[4].x)[jj], wj5 = (&wr[5].x)[jj], wj6 = (&wr[6].x)[jj], wj7 = (&wr[7].x)[jj];
                    acc[t][jj] += ha.x * wj0 + ha.y * wj1 + ha.z * wj2 + ha.w * wj3 +
                                  hc.x * wj4 + hc.y * wj5 + hc.z * wj6 + hc.w * wj7;
                }
            }
        }
        #pragma unroll
        for (int jj = 0; jj < 4; ++jj) {
            float s = 0.f;
            #pragma unroll
            for (int t = 0; t < 8; ++t) s += silu_f(acc[t][jj]);
            hps2[th8][j0 + jj] = s;
        }
    }
    __syncthreads();
    if (tid < H_) {
        float s = 0.f;
        #pragma unroll
        for (int g = 0; g < 8; ++g) s += hps2[g][tid];
        hp[tid] = s * (1.f / 64.f);
    }
    __syncthreads();

    {
        int j = tid & 127;
        int th = tid >> 7;
        const float* Wm = (th == 0) ? W_mu : W_sig;
        float a = 0.f;
        #pragma unroll 4
        for (int k = 0; k < H_; ++k) a += hp[k] * Wm[k * H_ + j];
        if (th == 0) muS[j] = a; else sgS[j] = a;
    }
    __syncthreads();
    if (tid < H_) {
        float sig = 0.1f + 0.9f / (1.f + __expf(-sgS[tid]));
        float v = muS[tid] + sig * eps[(size_t)br * H_ + tid];
        vS[tid] = v;
        if (tid < L_) Lz[(size_t)br * L_ + tid] = v;
        else          Dz[(size_t)br * D_ + (tid - L_)] = v;
    }
    __syncthreads();
    if (tid < L_) {
        float a = 0.f;
        #pragma unroll 4
        for (int k = 0; k < D_; ++k) a += vS[L_ + k] * W_dyn[k * L_ + tid];
        dynb[(size_t)br * L_ + tid] = a;
    }
}

// ---------------------------------------------------------------------------
// ode (MFMA): one block per batch, 8 waves. R10 structure with packed M^T
// (hi|lo per dword): phase-1 M writes 8 b64 -> 4 b128; v_perm unpack on read.
// ---------------------------------------------------------------------------
__global__ __launch_bounds__(512, 2) void ode_kernel(
    const float* __restrict__ Lz, const float* __restrict__ dynb,
    const float* __restrict__ W_msg, const float* __restrict__ W_self,
    const float* __restrict__ b_ode,
    const int* __restrict__ src, const int* __restrict__ dst,
    const float* __restrict__ space_w,
    float* __restrict__ traj) {
    const int b = blockIdx.x;
    const int tid = threadIdx.x;
    const int lane = tid & 63;
    const int w = tid >> 6;          // 0..7
    const int rb = w & 3;            // output row block (32 rows)
    const int cb = w >> 2;           // output col block (32 cols)
    const int l31 = lane & 31;
    const int h = lane >> 5;
    const int cc = cb * 32 + l31;    // this thread's output column (0..63)

    extern __shared__ char sm[];
    float* Af  = (float*)sm;                   // fp32 A staging [128][128]
    int* permS = (int*)(sm + PRM_OFF);         // 2048
    int* cnt4  = permS + ES_;                  // 512  (4 chunks x 128 rows)
    int* cntS  = cnt4 + 512;                   // 128
    int* rsS   = cntS + R_;                    // 129

    // ---- static weights -> LDS (hi/lo, transposed: WT[j][s][k] = W[k][j]) ----
    for (int idx = tid; idx < 4096; idx += 512) {
        int j = idx & 63, k = idx >> 6;
        float vs = W_self[k * 64 + j];
        f16 sh = (f16)vs;
        *(f16*)(sm + WS_OFF + swz256(j, 0, k * 2)) = sh;
        *(f16*)(sm + WS_OFF + swz256(j, 1, k * 2)) = (f16)(vs - (float)sh);
        float vm = W_msg[k * 64 + j];
        f16 mh = (f16)vm;
        *(f16*)(sm + WM_OFF + swz256(j, 0, k * 2)) = mh;
        *(f16*)(sm + WM_OFF + swz256(j, 1, k * 2)) = (f16)(vm - (float)mh);
    }

    // ---- CSR build, 4-way parallel (stable: chunks are consecutive ranges) ----
    {
        const int c4 = tid >> 7;          // chunk 0..3 (512 edges each)
        const int rr = tid & 127;
        int c = 0;
        const int eb = c4 * 512;
        for (int e = eb; e < eb + 512; ++e) c += (dst[e] == rr) ? 1 : 0;
        cnt4[c4 * 128 + rr] = c;
    }
    __syncthreads();
    if (tid < R_)
        cntS[tid] = cnt4[tid] + cnt4[128 + tid] + cnt4[256 + tid] + cnt4[384 + tid];
    __syncthreads();
    if (tid == 0) {
        int a = 0;
        for (int i = 0; i < R_; ++i) { rsS[i] = a; a += cntS[i]; }
        rsS[R_] = a;
    }
    __syncthreads();
    {
        const int c4 = tid >> 7;
        const int rr = tid & 127;
        int k = rsS[rr];
        for (int c = 0; c < c4; ++c) k += cnt4[c * 128 + rr];
        const int eb = c4 * 512;
        for (int e = eb; e < eb + 512; ++e)
            if (dst[e] == rr) permS[k++] = e;
    }
    for (int i = tid; i < 128 * 128; i += 512) Af[i] = 0.f;
    __syncthreads();
    if (tid < R_) {
        int e0_ = rsS[tid], e1_ = rsS[tid + 1];
        for (int e = e0_; e < e1_; ++e) {
            int pe = permS[e];
            Af[tid * 128 + src[pe]] += space_w[b * ES_ + pe];
        }
    }
    __syncthreads();

    // ---- A fragments -> VGPRs (hi/lo) ----
    f16x8 aH[8], aL[8];
    {
        int row = rb * 32 + l31;
        #pragma unroll
        for (int m = 0; m < 8; ++m) {
            const float* p = Af + row * 128 + m * 16 + h * 8;
            f16x8 vh, vl;
            #pragma unroll
            for (int i = 0; i < 8; ++i) {
                float v = p[i];
                f16 hi = (f16)v;
                vh[i] = hi;
                vl[i] = (f16)(v - (float)hi);
            }
            aH[m] = vh;
            aL[m] = vl;
        }
    }

    // ---- per-thread state in C-layout ----
    float xb[16], ks[16], dnb[16];
    {
        float bo = b_ode[cc];
        #pragma unroll
        for (int i = 0; i < 16; ++i) {
            int r = rb * 32 + (i & 3) + 8 * (i >> 2) + 4 * h;
            size_t o = ((size_t)(b * R_ + r)) * L_ + cc;
            xb[i] = Lz[o];
            dnb[i] = dynb[o] + bo;
        }
    }
    __syncthreads();  // Af dead; LDS 0..64KB becomes XP+MT

    // ---- write initial packed x ----
    #pragma unroll
    for (int i = 0; i < 16; ++i) {
        int r = rb * 32 + (i & 3) + 8 * (i >> 2) + 4 * h;
        f16 hi = (f16)xb[i];
        *(uint32_t*)(sm + XP_OFF + swzP(r, (uint32_t)cc * 4u)) =
            pack2_f16(hi, (f16)(xb[i] - (float)hi));
    }
    __syncthreads();

    const int rowx = rb * 32 + l31;   // A-operand row for this lane

    for (int n = 0; n < T_; ++n) {
        #pragma unroll
        for (int i = 0; i < 16; ++i) ks[i] = 0.f;
        for (int s4 = 0; s4 < 4; ++s4) {
            const float wk = (s4 == 1 || s4 == 2) ? 2.f : 1.f;
            const float cn = (s4 < 2) ? 0.05f : 0.1f;

            // ===== phase 1: S = dyn + x@Wself, M = x@Wmsg =====
            // burst-prefetch all x (8 b128 packed), unpack hi/lo via v_perm
            f16x8 xh[4], xl[4];
            #pragma unroll
            for (int m = 0; m < 4; ++m) {
                uint32_t cB = (uint32_t)(m * 16 + 8 * h) * 4u;
                uint4 p0 = *(const uint4*)(sm + XP_OFF + swzP(rowx, cB));
                uint4 p1 = *(const uint4*)(sm + XP_OFF + swzP(rowx, cB + 16u));
                union { uint32_t u[4]; f16x8 v; } H, L;
                H.u[0] = __builtin_amdgcn_perm(p0.y, p0.x, 0x05040100u);
                H.u[1] = __builtin_amdgcn_perm(p0.w, p0.z, 0x05040100u);
                H.u[2] = __builtin_amdgcn_perm(p1.y, p1.x, 0x05040100u);
                H.u[3] = __builtin_amdgcn_perm(p1.w, p1.z, 0x05040100u);
                L.u[0] = __builtin_amdgcn_perm(p0.y, p0.x, 0x07060302u);
                L.u[1] = __builtin_amdgcn_perm(p0.w, p0.z, 0x07060302u);
                L.u[2] = __builtin_amdgcn_perm(p1.y, p1.x, 0x07060302u);
                L.u[3] = __builtin_amdgcn_perm(p1.w, p1.z, 0x07060302u);
                xh[m] = H.v; xl[m] = L.v;
            }
            f32x16 aS, aM = {};
            #pragma unroll
            for (int i = 0; i < 16; ++i) aS[i] = dnb[i];
            #pragma unroll
            for (int m = 0; m < 4; ++m) {
                uint32_t kB = (m * 16 + 8 * h) * 2;
                f16x8 wsH = *(const f16x8*)(sm + WS_OFF + swz256(cc, 0, kB));
                f16x8 wsL = *(const f16x8*)(sm + WS_OFF + swz256(cc, 1, kB));
                f16x8 wmH = *(const f16x8*)(sm + WM_OFF + swz256(cc, 0, kB));
                f16x8 wmL = *(const f16x8*)(sm + WM_OFF + swz256(cc, 1, kB));
                aS = __builtin_amdgcn_mfma_f32_32x32x16_f16(xh[m], wsH, aS, 0, 0, 0);
                aM = __builtin_amdgcn_mfma_f32_32x32x16_f16(xh[m], wmH, aM, 0, 0, 0);
                aS = __builtin_amdgcn_mfma_f32_32x32x16_f16(xl[m], wsH, aS, 0, 0, 0);
                aM = __builtin_amdgcn_mfma_f32_32x32x16_f16(xl[m], wmH, aM, 0, 0, 0);
                aS = __builtin_amdgcn_mfma_f32_32x32x16_f16(xh[m], wsL, aS, 0, 0, 0);
                aM = __builtin_amdgcn_mfma_f32_32x32x16_f16(xh[m], wmL, aM, 0, 0, 0);
            }
            // write packed M^T: per q, 4 consecutive rows -> one b128
            #pragma unroll
            for (int q = 0; q < 4; ++q) {
                int rbase = rb * 32 + 8 * q + 4 * h;
                uint4 pk;
                {
                    float v0 = aM[4 * q + 0], v1 = aM[4 * q + 1];
                    float v2 = aM[4 * q + 2], v3 = aM[4 * q + 3];
                    f16 h0 = (f16)v0, h1_ = (f16)v1, h2 = (f16)v2, h3 = (f16)v3;
                    pk.x = pack2_f16(h0, (f16)(v0 - (float)h0));
                    pk.y = pack2_f16(h1_, (f16)(v1 - (float)h1_));
                    pk.z = pack2_f16(h2, (f16)(v2 - (float)h2));
                    pk.w = pack2_f16(h3, (f16)(v3 - (float)h3));
                }
                *(uint4*)(sm + MT_OFF + swzTP(cc, (uint32_t)rbase * 4u)) = pk;
            }
            __syncthreads();

            // ===== phase 2: accK = S + A@M (3 independent chains) =====
            f32x16 e0 = {}, e1 = {}, e2 = {};
            #pragma unroll
            for (int m = 0; m < 8; ++m) {
                uint32_t rB = (uint32_t)(m * 16 + 8 * h) * 4u;
                uint4 p0 = *(const uint4*)(sm + MT_OFF + swzTP(cc, rB));
                uint4 p1 = *(const uint4*)(sm + MT_OFF + swzTP(cc, rB + 16u));
                union { uint32_t u[4]; f16x8 v; } H, L;
                H.u[0] = __builtin_amdgcn_perm(p0.y, p0.x, 0x05040100u);
                H.u[1] = __builtin_amdgcn_perm(p0.w, p0.z, 0x05040100u);
                H.u[2] = __builtin_amdgcn_perm(p1.y, p1.x, 0x05040100u);
                H.u[3] = __builtin_amdgcn_perm(p1.w, p1.z, 0x05040100u);
                L.u[0] = __builtin_amdgcn_perm(p0.y, p0.x, 0x07060302u);
                L.u[1] = __builtin_amdgcn_perm(p0.w, p0.z, 0x07060302u);
                L.u[2] = __builtin_amdgcn_perm(p1.y, p1.x, 0x07060302u);
                L.u[3] = __builtin_amdgcn_perm(p1.w, p1.z, 0x07060302u);
                f16x8 mtH = H.v, mtL = L.v;
                if (m < 3) {
                    e0 = __builtin_amdgcn_mfma_f32_32x32x16_f16(aH[m], mtH, e0, 0, 0, 0);
                    e0 = __builtin_amdgcn_mfma_f32_32x32x16_f16(aL[m], mtH, e0, 0, 0, 0);
                    e0 = __builtin_amdgcn_mfma_f32_32x32x16_f16(aH[m], mtL, e0, 0, 0, 0);
                } else if (m < 6) {
                    e1 = __builtin_amdgcn_mfma_f32_32x32x16_f16(aH[m], mtH, e1, 0, 0, 0);
                    e1 = __builtin_amdgcn_mfma_f32_32x32x16_f16(aL[m], mtH, e1, 0, 0, 0);
                    e1 = __builtin_amdgcn_mfma_f32_32x32x16_f16(aH[m], mtL, e1, 0, 0, 0);
                } else {
                    e2 = __builtin_amdgcn_mfma_f32_32x32x16_f16(aH[m], mtH, e2, 0, 0, 0);
                    e2 = __builtin_amdgcn_mfma_f32_32x32x16_f16(aL[m], mtH, e2, 0, 0, 0);
                    e2 = __builtin_amdgcn_mfma_f32_32x32x16_f16(aH[m], mtL, e2, 0, 0, 0);
                }
            }
            // epilogue: tanh, RK4, write packed x
            float xn_[16];
            #pragma unroll
            for (int i = 0; i < 16; ++i) {
                float kv = tanh_f(aS[i] + e0[i] + e1[i] + e2[i]);
                ks[i] += wk * kv;
                xn_[i] = (s4 < 3) ? (xb[i] + cn * kv) : (xb[i] + (0.1f / 6.f) * ks[i]);
            }
            if (s4 == 3) {
                #pragma unroll
                for (int i = 0; i < 16; ++i) xb[i] = xn_[i];
            }
            #pragma unroll
            for (int i = 0; i < 16; ++i) {
                int r = rb * 32 + (i & 3) + 8 * (i >> 2) + 4 * h;
                f16 hi = (f16)xn_[i];
                *(uint32_t*)(sm + XP_OFF + swzP(r, (uint32_t)cc * 4u)) =
                    pack2_f16(hi, (f16)(xn_[i] - (float)hi));
            }
            if (s4 == 3) {
                #pragma unroll
                for (int i = 0; i < 16; ++i) {
                    int r = rb * 32 + (i & 3) + 8 * (i >> 2) + 4 * h;
                    traj[(((size_t)b * T_ + n) * R_ + r) * L_ + cc] = xb[i];
                }
            }
            __syncthreads();
        }
    }
}

// ---------------------------------------------------------------------------
// decoder: one block per (b,r), one-hot rid exploited as row lookup.
// ---------------------------------------------------------------------------
__global__ __launch_bounds__(256) void decoder_kernel(
    const float* __restrict__ traj, const float* __restrict__ Dz,
    const float* __restrict__ W_d1, const float* __restrict__ b_d1,
    const float* __restrict__ W_d2, const float* __restrict__ b_d2,
    float* __restrict__ y) {
    int br = blockIdx.x;
    int b = br >> 7;
    int r = br & 127;
    int tid = threadIdx.x;
    __shared__ __align__(16) float trajS[32 * L_];
    __shared__ __align__(16) float hS[32 * H_];
    __shared__ float dzS[D_];
    __shared__ float baseS[H_];

    int j = tid & 127;
    int th = tid >> 7;
    if (tid < D_) dzS[tid] = Dz[(size_t)br * D_ + tid];
    __syncthreads();

    float wcol[64];
    #pragma unroll
    for (int k = 0; k < 64; ++k) wcol[k] = W_d1[k * H_ + j];
    float wt = W_d1[128 * H_ + j];
    if (th == 0) {
        float a = b_d1[j] + W_d1[(129 + r) * H_ + j];
        #pragma unroll 4
        for (int k = 0; k < D_; ++k) a += dzS[k] * W_d1[(64 + k) * H_ + j];
        baseS[j] = a;
    }
    __syncthreads();
    float bb = baseS[j];

    for (int half = 0; half < 2; ++half) {
        for (int i = tid; i < 32 * L_; i += 256) {
            int tt = i >> 6, l = i & 63;
            trajS[i] = traj[(((size_t)b * T_ + half * 32 + tt) * R_ + r) * L_ + l];
        }
        __syncthreads();
        #pragma unroll
        for (int tt = 0; tt < 16; ++tt) {
            int tl = th * 16 + tt;
            int t = half * 32 + tl;
            float a = bb + (float)t * (1.f / 64.f) * wt;
            const float4* tr4 = (const float4*)(&trajS[tl * L_]);
            #pragma unroll
            for (int kb = 0; kb < 16; ++kb) {
                float4 tv = tr4[kb];
                a += tv.x * wcol[kb * 4 + 0] + tv.y * wcol[kb * 4 + 1] +
                     tv.z * wcol[kb * 4 + 2] + tv.w * wcol[kb * 4 + 3];
            }
            hS[tl * H_ + j] = silu_f(a);
        }
        __syncthreads();
        {
            int o = tid & 31, q = tid >> 5;
            float acc2[4];
            float bd2 = b_d2[o];
            #pragma unroll
            for (int u = 0; u < 4; ++u) acc2[u] = bd2;
            for (int jc = 0; jc < 4; ++jc) {
                float wreg[32];
                #pragma unroll
                for (int i2 = 0; i2 < 32; ++i2) wreg[i2] = W_d2[(jc * 32 + i2) * OUT_ + o];
                #pragma unroll
                for (int u = 0; u < 4; ++u) {
                    int tl = q * 4 + u;
                    const float4* h4 = (const float4*)(&hS[tl * H_ + jc * 32]);
                    float s2 = 0.f;
                    #pragma unroll
                    for (int w4 = 0; w4 < 8; ++w4) {
                        float4 hv = h4[w4];
                        s2 += hv.x * wreg[w4 * 4 + 0] + hv.y * wreg[w4 * 4 + 1] +
                              hv.z * wreg[w4 * 4 + 2] + hv.w * wreg[w4 * 4 + 3];
                    }
                    acc2[u] += s2;
                }
            }
            #pragma unroll
            for (int u = 0; u < 4; ++u) {
                int t = half * 32 + q * 4 + u;
                y[((size_t)br * T_ + t) * OUT_ + o] = acc2[u];
            }
        }
        __syncthreads();
    }
}

extern "C" void kernel_launch(void* const* d_in, const int* in_sizes, int n_in,
                              void* d_out, int out_size, void* d_ws, size_t ws_size,
                              hipStream_t stream) {
    const float* node_feats = (const float*)d_in[0];
    const float* eps_       = (const float*)d_in[1];
    const float* space_w    = (const float*)d_in[2];
    const int*   src        = (const int*)d_in[3];
    const int*   dst        = (const int*)d_in[4];
    const float* W_e1 = (const float*)d_in[5];
    const float* b_e1 = (const float*)d_in[6];
    const float* W_e2 = (const float*)d_in[7];
    const float* b_e2 = (const float*)d_in[8];
    const float* W_mu = (const float*)d_in[9];
    const float* W_sig = (const float*)d_in[10];
    const float* W_msg = (const float*)d_in[11];
    const float* W_self = (const float*)d_in[12];
    const float* W_dyn = (const float*)d_in[13];
    const float* b_ode = (const float*)d_in[14];
    const float* W_d1 = (const float*)d_in[15];
    const float* b_d1 = (const float*)d_in[16];
    const float* W_d2 = (const float*)d_in[17];
    const float* b_d2 = (const float*)d_in[18];
    float* out = (float*)d_out;

    float* f_ws = (float*)d_ws;
    float* Lz    = f_ws;                              // 65536
    float* Dz    = Lz + B_ * R_ * L_;                 // 65536
    float* dynb  = Dz + B_ * R_ * D_;                 // 65536
    float* traj  = dynb + B_ * R_ * L_;               // 4194304

    encoder_kernel<<<B_ * R_, 256, 0, stream>>>(node_feats, eps_, W_e1, b_e1, W_e2, b_e2,
                                                W_mu, W_sig, W_dyn, Lz, Dz, dynb);
    ode_kernel<<<B_, 512, ODE_LDS, stream>>>(Lz, dynb, W_msg, W_self, b_ode,
                                             src, dst, space_w, traj);
    decoder_kernel<<<B_ * R_, 256, 0, stream>>>(traj, Dz, W_d1, b_d1, W_d2, b_d2, out);
}